// Round 1
// baseline (2298.427 us; speedup 1.0000x reference)
//
#include <hip/hip_runtime.h>

#define NN 50000
#define NE 800000
// dims: IN=256, HID=128, OUT=64

__global__ void deg_kernel(const int* __restrict__ src, const int* __restrict__ dst,
                           float* __restrict__ deg_out, float* __restrict__ deg_in, int E) {
    int stride = gridDim.x * blockDim.x;
    for (int i = blockIdx.x * blockDim.x + threadIdx.x; i < E; i += stride) {
        atomicAdd(&deg_out[src[i]], 1.0f);
        atomicAdd(&deg_in[dst[i]], 1.0f);
    }
}

__global__ void norm_kernel(float* a, float* b, int n) {
    int i = blockIdx.x * blockDim.x + threadIdx.x;
    if (i < n) {
        a[i] = rsqrtf(fmaxf(a[i], 1.0f));
        b[i] = rsqrtf(fmaxf(b[i], 1.0f));
    }
}

// C[M x BN] = (A[M x K] @ B[K x BN]) * scale[row]
// BM=64 rows per block, BK=16 k-chunk, 256 threads.
template <int BN, int K>
__global__ __launch_bounds__(256) void gemm_scale_kernel(
    const float* __restrict__ A, const float* __restrict__ B,
    const float* __restrict__ scale, float* __restrict__ C, int M) {
    constexpr int BM = 64, BK = 16;
    constexpr int CT = BN / 4;     // col-thread count (cols of 4)
    constexpr int RT = 256 / CT;   // row-thread count
    constexpr int RPT = BM / RT;   // rows per thread (8 for BN=128, 4 for BN=64)

    __shared__ float As[BK * BM];  // k-major, transposed: As[k][row]
    __shared__ float Bs[BK * BN];  // Bs[k][col]

    const int tid = threadIdx.x;
    const int tcol = tid % CT;
    const int trow = tid / CT;
    const int col0 = tcol * 4;
    const int row0 = trow * RPT;
    const int block_row = blockIdx.x * BM;

    float acc[RPT][4];
#pragma unroll
    for (int r = 0; r < RPT; r++)
#pragma unroll
        for (int c = 0; c < 4; c++) acc[r][c] = 0.0f;

    for (int kk = 0; kk < K; kk += BK) {
        // A tile: 64 rows x 16 k = 256 float4 (4 consecutive k per float4)
        {
            int r = tid >> 2, kq = tid & 3;
            int rg = block_row + r;
            float4 a = make_float4(0.f, 0.f, 0.f, 0.f);
            if (rg < M) a = *(const float4*)&A[(size_t)rg * K + kk + kq * 4];
            As[(kq * 4 + 0) * BM + r] = a.x;
            As[(kq * 4 + 1) * BM + r] = a.y;
            As[(kq * 4 + 2) * BM + r] = a.z;
            As[(kq * 4 + 3) * BM + r] = a.w;
        }
        // B tile: BK x BN
        {
            constexpr int F4 = BK * BN / 4;
#pragma unroll
            for (int f = tid; f < F4; f += 256) {
                int kq = f / (BN / 4), n4 = f % (BN / 4);
                *(float4*)&Bs[kq * BN + n4 * 4] =
                    *(const float4*)&B[(size_t)(kk + kq) * BN + n4 * 4];
            }
        }
        __syncthreads();
#pragma unroll
        for (int k = 0; k < BK; k++) {
            float4 b = *(const float4*)&Bs[k * BN + col0];
#pragma unroll
            for (int r = 0; r < RPT; r += 4) {
                float4 a = *(const float4*)&As[k * BM + row0 + r];
                acc[r + 0][0] += a.x * b.x; acc[r + 0][1] += a.x * b.y;
                acc[r + 0][2] += a.x * b.z; acc[r + 0][3] += a.x * b.w;
                acc[r + 1][0] += a.y * b.x; acc[r + 1][1] += a.y * b.y;
                acc[r + 1][2] += a.y * b.z; acc[r + 1][3] += a.y * b.w;
                acc[r + 2][0] += a.z * b.x; acc[r + 2][1] += a.z * b.y;
                acc[r + 2][2] += a.z * b.z; acc[r + 2][3] += a.z * b.w;
                acc[r + 3][0] += a.w * b.x; acc[r + 3][1] += a.w * b.y;
                acc[r + 3][2] += a.w * b.z; acc[r + 3][3] += a.w * b.w;
            }
        }
        __syncthreads();
    }

#pragma unroll
    for (int r = 0; r < RPT; r++) {
        int rg = block_row + row0 + r;
        if (rg < M) {
            float s = scale[rg];
            float4 v = make_float4(acc[r][0] * s, acc[r][1] * s,
                                   acc[r][2] * s, acc[r][3] * s);
            *(float4*)&C[(size_t)rg * BN + col0] = v;
        }
    }
}

// agg[dst[e]][:] += hs[src[e]][:], float4 granularity. D4 = D/4 (power of 2).
template <int D4>
__global__ void scatter_kernel(const float4* __restrict__ hs, const int* __restrict__ src,
                               const int* __restrict__ dst, float* __restrict__ agg, int E) {
    unsigned total = (unsigned)E * D4;
    unsigned stride = gridDim.x * blockDim.x;
    for (unsigned i = blockIdx.x * blockDim.x + threadIdx.x; i < total; i += stride) {
        unsigned e = i / D4, j = i % D4;
        int s = src[e], d = dst[e];
        float4 v = hs[(size_t)s * D4 + j];
        float* p = &agg[((size_t)d * D4 + j) * 4];
        atomicAdd(p + 0, v.x);
        atomicAdd(p + 1, v.y);
        atomicAdd(p + 2, v.z);
        atomicAdd(p + 3, v.w);
    }
}

// out = (agg * norm_dst[node] + bias[col]); optional relu. Works in-place.
template <int D4, bool RELU>
__global__ void finalize_kernel(const float4* agg, const float* __restrict__ norm,
                                const float4* __restrict__ bias, float4* out, int total4) {
    int i = blockIdx.x * blockDim.x + threadIdx.x;
    if (i >= total4) return;
    int nidx = i / D4, j = i % D4;
    float s = norm[nidx];
    float4 a = agg[i];
    float4 b = bias[j];
    float4 r;
    r.x = a.x * s + b.x;
    r.y = a.y * s + b.y;
    r.z = a.z * s + b.z;
    r.w = a.w * s + b.w;
    if (RELU) {
        r.x = fmaxf(r.x, 0.f);
        r.y = fmaxf(r.y, 0.f);
        r.z = fmaxf(r.z, 0.f);
        r.w = fmaxf(r.w, 0.f);
    }
    out[i] = r;
}

extern "C" void kernel_launch(void* const* d_in, const int* in_sizes, int n_in,
                              void* d_out, int out_size, void* d_ws, size_t ws_size,
                              hipStream_t stream) {
    const float* x  = (const float*)d_in[0];   // [50000,256]
    const float* W1 = (const float*)d_in[1];   // [256,128]
    const float* b1 = (const float*)d_in[2];   // [128]
    const float* W2 = (const float*)d_in[3];   // [128,64]
    const float* b2 = (const float*)d_in[4];   // [64]
    const int* src  = (const int*)d_in[5];     // [800000]
    const int* dst  = (const int*)d_in[6];     // [800000]
    float* out = (float*)d_out;                // [50000,64]
    float* ws = (float*)d_ws;

    // ws layout (floats): norms(2x51200) | hs1(6.4M) | agg1/hs2(6.4M)  => ~51.6 MB
    float* deg_out = ws;                       // becomes norm_src
    float* deg_in  = ws + 51200;               // becomes norm_dst
    float* hs1     = ws + 102400;              // [50000,128], reused as h1
    float* agg1    = ws + 102400 + 6400000;    // [50000,128], reused as hs2
    float* hs2     = agg1;

    hipMemsetAsync(deg_out, 0, 102400 * sizeof(float), stream);   // both deg arrays
    hipMemsetAsync(agg1, 0, 6400000 * sizeof(float), stream);
    hipMemsetAsync(out, 0, 3200000 * sizeof(float), stream);

    deg_kernel<<<1024, 256, 0, stream>>>(src, dst, deg_out, deg_in, NE);
    norm_kernel<<<(NN + 255) / 256, 256, 0, stream>>>(deg_out, deg_in, NN);

    // layer 1
    gemm_scale_kernel<128, 256><<<(NN + 63) / 64, 256, 0, stream>>>(x, W1, deg_out, hs1, NN);
    scatter_kernel<32><<<4096, 256, 0, stream>>>((const float4*)hs1, src, dst, agg1, NE);
    finalize_kernel<32, true><<<(NN * 32 + 255) / 256, 256, 0, stream>>>(
        (const float4*)agg1, deg_in, (const float4*)b1, (float4*)hs1, NN * 32);

    // layer 2 (h1 lives in hs1; hs2 overwrites agg1 after finalize read it)
    gemm_scale_kernel<64, 128><<<(NN + 63) / 64, 256, 0, stream>>>(hs1, W2, deg_out, hs2, NN);
    scatter_kernel<16><<<4096, 256, 0, stream>>>((const float4*)hs2, src, dst, out, NE);
    finalize_kernel<16, false><<<(NN * 16 + 255) / 256, 256, 0, stream>>>(
        (const float4*)out, deg_in, (const float4*)b2, (float4*)out, NN * 16);
}

// Round 2
// 525.092 us; speedup vs baseline: 4.3772x; 4.3772x over previous
//
#include <hip/hip_runtime.h>

#define NN 50000
#define NE 800000
// dims: IN=256, HID=128, OUT=64

// ---------------- CSR build ----------------

__global__ void hist_kernel(const int* __restrict__ src, const int* __restrict__ dst,
                            int* __restrict__ cnt_src, int* __restrict__ cnt_dst, int E) {
    int stride = gridDim.x * blockDim.x;
    for (int i = blockIdx.x * blockDim.x + threadIdx.x; i < E; i += stride) {
        atomicAdd(&cnt_src[src[i]], 1);
        atomicAdd(&cnt_dst[dst[i]], 1);
    }
}

__global__ void norm_kernel(const int* __restrict__ cs, const int* __restrict__ cd,
                            float* __restrict__ ns, float* __restrict__ nd, int n) {
    int i = blockIdx.x * blockDim.x + threadIdx.x;
    if (i < n) {
        ns[i] = rsqrtf(fmaxf((float)cs[i], 1.0f));
        nd[i] = rsqrtf(fmaxf((float)cd[i], 1.0f));
    }
}

// Single-block exclusive scan of cnt (n <= 1024*49) -> row_ofs[0..n], cursor[0..n-1]
__global__ __launch_bounds__(1024) void scan_kernel(const int* __restrict__ cnt,
                                                    int* __restrict__ row_ofs,
                                                    int* __restrict__ cursor, int n) {
    __shared__ int lds[1024];
    const int CH = 49;
    int tid = threadIdx.x;
    int base = tid * CH;
    int s = 0;
    for (int j = 0; j < CH; j++) {
        int i = base + j;
        if (i < n) s += cnt[i];
    }
    lds[tid] = s;
    __syncthreads();
    for (int ofs = 1; ofs < 1024; ofs <<= 1) {
        int t = (tid >= ofs) ? lds[tid - ofs] : 0;
        __syncthreads();
        lds[tid] += t;
        __syncthreads();
    }
    int run = lds[tid] - s;  // exclusive prefix for this chunk
    for (int j = 0; j < CH; j++) {
        int i = base + j;
        if (i < n) {
            row_ofs[i] = run;
            cursor[i] = run;
            run += cnt[i];
        }
    }
    if (tid == 1023) row_ofs[n] = lds[1023];
}

__global__ void fill_kernel(const int* __restrict__ src, const int* __restrict__ dst,
                            int* __restrict__ cursor, int* __restrict__ eidx, int E) {
    int stride = gridDim.x * blockDim.x;
    for (int i = blockIdx.x * blockDim.x + threadIdx.x; i < E; i += stride) {
        int pos = atomicAdd(&cursor[dst[i]], 1);
        eidx[pos] = src[i];
    }
}

// ---------------- GEMM with row-scale epilogue ----------------
// C[M x BN] = (A[M x K] @ B[K x BN]) * scale[row]
template <int BN, int K>
__global__ __launch_bounds__(256) void gemm_scale_kernel(
    const float* __restrict__ A, const float* __restrict__ B,
    const float* __restrict__ scale, float* __restrict__ C, int M) {
    constexpr int BM = 64, BK = 16;
    constexpr int CT = BN / 4;
    constexpr int RT = 256 / CT;
    constexpr int RPT = BM / RT;

    __shared__ float As[BK * BM];
    __shared__ float Bs[BK * BN];

    const int tid = threadIdx.x;
    const int tcol = tid % CT;
    const int trow = tid / CT;
    const int col0 = tcol * 4;
    const int row0 = trow * RPT;
    const int block_row = blockIdx.x * BM;

    float acc[RPT][4];
#pragma unroll
    for (int r = 0; r < RPT; r++)
#pragma unroll
        for (int c = 0; c < 4; c++) acc[r][c] = 0.0f;

    for (int kk = 0; kk < K; kk += BK) {
        {
            int r = tid >> 2, kq = tid & 3;
            int rg = block_row + r;
            float4 a = make_float4(0.f, 0.f, 0.f, 0.f);
            if (rg < M) a = *(const float4*)&A[(size_t)rg * K + kk + kq * 4];
            As[(kq * 4 + 0) * BM + r] = a.x;
            As[(kq * 4 + 1) * BM + r] = a.y;
            As[(kq * 4 + 2) * BM + r] = a.z;
            As[(kq * 4 + 3) * BM + r] = a.w;
        }
        {
            constexpr int F4 = BK * BN / 4;
#pragma unroll
            for (int f = tid; f < F4; f += 256) {
                int kq = f / (BN / 4), n4 = f % (BN / 4);
                *(float4*)&Bs[kq * BN + n4 * 4] =
                    *(const float4*)&B[(size_t)(kk + kq) * BN + n4 * 4];
            }
        }
        __syncthreads();
#pragma unroll
        for (int k = 0; k < BK; k++) {
            float4 b = *(const float4*)&Bs[k * BN + col0];
#pragma unroll
            for (int r = 0; r < RPT; r += 4) {
                float4 a = *(const float4*)&As[k * BM + row0 + r];
                acc[r + 0][0] += a.x * b.x; acc[r + 0][1] += a.x * b.y;
                acc[r + 0][2] += a.x * b.z; acc[r + 0][3] += a.x * b.w;
                acc[r + 1][0] += a.y * b.x; acc[r + 1][1] += a.y * b.y;
                acc[r + 1][2] += a.y * b.z; acc[r + 1][3] += a.y * b.w;
                acc[r + 2][0] += a.z * b.x; acc[r + 2][1] += a.z * b.y;
                acc[r + 2][2] += a.z * b.z; acc[r + 2][3] += a.z * b.w;
                acc[r + 3][0] += a.w * b.x; acc[r + 3][1] += a.w * b.y;
                acc[r + 3][2] += a.w * b.z; acc[r + 3][3] += a.w * b.w;
            }
        }
        __syncthreads();
    }

#pragma unroll
    for (int r = 0; r < RPT; r++) {
        int rg = block_row + row0 + r;
        if (rg < M) {
            float s = scale[rg];
            float4 v = make_float4(acc[r][0] * s, acc[r][1] * s,
                                   acc[r][2] * s, acc[r][3] * s);
            *(float4*)&C[(size_t)rg * BN + col0] = v;
        }
    }
}

// ---------------- CSR gather-sum aggregation + fused epilogue ----------------
// One wave per dst node. Lanes own feature dims. out = relu?(sum * norm[n] + bias)
template <int D, bool RELU>
__global__ __launch_bounds__(256) void gather_kernel(
    const float* __restrict__ hs, const int* __restrict__ eidx,
    const int* __restrict__ row_ofs, const float* __restrict__ norm,
    const float* __restrict__ bias, float* __restrict__ out, int n) {
    int wave = (blockIdx.x * blockDim.x + threadIdx.x) >> 6;
    int lane = threadIdx.x & 63;
    if (wave >= n) return;
    int beg = row_ofs[wave];
    int end = row_ofs[wave + 1];
    float sc = norm[wave];

    if (D == 128) {
        const float2* h2 = (const float2*)hs;
        float2 acc = make_float2(0.f, 0.f);
        int e = beg;
        for (; e + 1 < end; e += 2) {
            int s0 = eidx[e], s1 = eidx[e + 1];
            float2 v0 = h2[(size_t)s0 * 64 + lane];
            float2 v1 = h2[(size_t)s1 * 64 + lane];
            acc.x += v0.x + v1.x;
            acc.y += v0.y + v1.y;
        }
        if (e < end) {
            float2 v = h2[(size_t)eidx[e] * 64 + lane];
            acc.x += v.x;
            acc.y += v.y;
        }
        float2 b = ((const float2*)bias)[lane];
        float2 r = make_float2(acc.x * sc + b.x, acc.y * sc + b.y);
        if (RELU) { r.x = fmaxf(r.x, 0.f); r.y = fmaxf(r.y, 0.f); }
        ((float2*)out)[(size_t)wave * 64 + lane] = r;
    } else {  // D == 64
        float acc = 0.f;
        int e = beg;
        for (; e + 1 < end; e += 2) {
            int s0 = eidx[e], s1 = eidx[e + 1];
            acc += hs[(size_t)s0 * 64 + lane] + hs[(size_t)s1 * 64 + lane];
        }
        if (e < end) acc += hs[(size_t)eidx[e] * 64 + lane];
        float r = acc * sc + bias[lane];
        if (RELU) r = fmaxf(r, 0.f);
        out[(size_t)wave * 64 + lane] = r;
    }
}

extern "C" void kernel_launch(void* const* d_in, const int* in_sizes, int n_in,
                              void* d_out, int out_size, void* d_ws, size_t ws_size,
                              hipStream_t stream) {
    const float* x  = (const float*)d_in[0];   // [50000,256]
    const float* W1 = (const float*)d_in[1];   // [256,128]
    const float* b1 = (const float*)d_in[2];   // [128]
    const float* W2 = (const float*)d_in[3];   // [128,64]
    const float* b2 = (const float*)d_in[4];   // [64]
    const int* src  = (const int*)d_in[5];     // [800000]
    const int* dst  = (const int*)d_in[6];     // [800000]
    float* out = (float*)d_out;                // [50000,64]
    char* ws = (char*)d_ws;

    // ws layout (4-byte units)
    int*   cnt_src  = (int*)(ws);                       // 50176
    int*   cnt_dst  = (int*)(ws + 4 * 50176);           // 50176
    float* norm_src = (float*)(ws + 4 * 100352);        // 50176
    float* norm_dst = (float*)(ws + 4 * 150528);        // 50176
    int*   row_ofs  = (int*)(ws + 4 * 200704);          // 50432 (need 50001)
    int*   cursor   = (int*)(ws + 4 * 251136);          // 50176
    int*   eidx     = (int*)(ws + 4 * 301312);          // 800000
    float* hs1      = (float*)(ws + 4 * 1101312);       // [50000,128]; reused as hs2
    float* h1       = (float*)(ws + 4 * 7501312);       // [50000,128]
    float* hs2      = hs1;                              // [50000,64] fits
    // total: 13,901,312 * 4B ≈ 55.6 MB

    hipMemsetAsync(cnt_src, 0, 2 * 50176 * sizeof(int), stream);  // both cnt arrays

    hist_kernel<<<1024, 256, 0, stream>>>(src, dst, cnt_src, cnt_dst, NE);
    norm_kernel<<<(NN + 255) / 256, 256, 0, stream>>>(cnt_src, cnt_dst, norm_src, norm_dst, NN);
    scan_kernel<<<1, 1024, 0, stream>>>(cnt_dst, row_ofs, cursor, NN);
    fill_kernel<<<1024, 256, 0, stream>>>(src, dst, cursor, eidx, NE);

    // layer 1: hs1 = (x @ W1) * norm_src ; h1 = relu(gather(hs1)*norm_dst + b1)
    gemm_scale_kernel<128, 256><<<(NN + 63) / 64, 256, 0, stream>>>(x, W1, norm_src, hs1, NN);
    gather_kernel<128, true><<<(NN + 3) / 4, 256, 0, stream>>>(
        hs1, eidx, row_ofs, norm_dst, b1, h1, NN);

    // layer 2: hs2 = (h1 @ W2) * norm_src ; out = gather(hs2)*norm_dst + b2
    gemm_scale_kernel<64, 128><<<(NN + 63) / 64, 256, 0, stream>>>(h1, W2, norm_src, hs2, NN);
    gather_kernel<64, false><<<(NN + 3) / 4, 256, 0, stream>>>(
        hs2, eidx, row_ofs, norm_dst, b2, out, NN);
}

// Round 3
// 410.385 us; speedup vs baseline: 5.6007x; 1.2795x over previous
//
#include <hip/hip_runtime.h>

#define NN 50000
#define NE 800000
// dims: IN=256, HID=128, OUT=64

// ---------------- CSR build ----------------

__global__ void hist_kernel(const int* __restrict__ src, const int* __restrict__ dst,
                            int* __restrict__ cnt_src, int* __restrict__ cnt_dst, int E) {
    int stride = gridDim.x * blockDim.x;
    for (int i = blockIdx.x * blockDim.x + threadIdx.x; i < E; i += stride) {
        atomicAdd(&cnt_src[src[i]], 1);
        atomicAdd(&cnt_dst[dst[i]], 1);
    }
}

__global__ void norm_kernel(const int* __restrict__ cs, const int* __restrict__ cd,
                            float* __restrict__ ns, float* __restrict__ nd, int n) {
    int i = blockIdx.x * blockDim.x + threadIdx.x;
    if (i < n) {
        ns[i] = rsqrtf(fmaxf((float)cs[i], 1.0f));
        nd[i] = rsqrtf(fmaxf((float)cd[i], 1.0f));
    }
}

// 3-phase scan: A) per-block exclusive scan + block sums, B) scan block sums,
// C) add block offsets -> row_ofs, cursor.
__global__ __launch_bounds__(256) void scanA_kernel(const int* __restrict__ cnt,
                                                    int* __restrict__ pref,
                                                    int* __restrict__ blk_sum, int n) {
    __shared__ int lds[256];
    int i = blockIdx.x * 256 + threadIdx.x;
    int v = (i < n) ? cnt[i] : 0;
    lds[threadIdx.x] = v;
    __syncthreads();
    for (int ofs = 1; ofs < 256; ofs <<= 1) {
        int t = (threadIdx.x >= ofs) ? lds[threadIdx.x - ofs] : 0;
        __syncthreads();
        lds[threadIdx.x] += t;
        __syncthreads();
    }
    if (i < n) pref[i] = lds[threadIdx.x] - v;  // exclusive
    if (threadIdx.x == 255) blk_sum[blockIdx.x] = lds[255];
}

__global__ __launch_bounds__(256) void scanB_kernel(const int* __restrict__ blk_sum,
                                                    int* __restrict__ blk_ofs, int nb) {
    __shared__ int lds[256];
    int v = (threadIdx.x < nb) ? blk_sum[threadIdx.x] : 0;
    lds[threadIdx.x] = v;
    __syncthreads();
    for (int ofs = 1; ofs < 256; ofs <<= 1) {
        int t = (threadIdx.x >= ofs) ? lds[threadIdx.x - ofs] : 0;
        __syncthreads();
        lds[threadIdx.x] += t;
        __syncthreads();
    }
    if (threadIdx.x < nb) blk_ofs[threadIdx.x] = lds[threadIdx.x] - v;
}

__global__ __launch_bounds__(256) void scanC_kernel(int* __restrict__ row_ofs,
                                                    const int* __restrict__ blk_ofs,
                                                    int* __restrict__ cursor, int n) {
    int i = blockIdx.x * 256 + threadIdx.x;
    if (i < n) {
        int r = row_ofs[i] + blk_ofs[blockIdx.x];
        row_ofs[i] = r;
        cursor[i] = r;
    }
    if (i == 0) row_ofs[n] = NE;  // every edge lands in some row
}

__global__ void fill_kernel(const int* __restrict__ src, const int* __restrict__ dst,
                            int* __restrict__ cursor, int* __restrict__ eidx, int E) {
    int stride = gridDim.x * blockDim.x;
    for (int i = blockIdx.x * blockDim.x + threadIdx.x; i < E; i += stride) {
        int pos = atomicAdd(&cursor[dst[i]], 1);
        eidx[pos] = src[i];
    }
}

// ---------------- GEMM with row-scale epilogue ----------------
// C[M x BN] = (A[M x K] @ B[K x BN]) * scale[row]
template <int BN, int K>
__global__ __launch_bounds__(256) void gemm_scale_kernel(
    const float* __restrict__ A, const float* __restrict__ B,
    const float* __restrict__ scale, float* __restrict__ C, int M) {
    constexpr int BM = 64, BK = 16;
    constexpr int CT = BN / 4;
    constexpr int RT = 256 / CT;
    constexpr int RPT = BM / RT;

    __shared__ float As[BK * BM];
    __shared__ float Bs[BK * BN];

    const int tid = threadIdx.x;
    const int tcol = tid % CT;
    const int trow = tid / CT;
    const int col0 = tcol * 4;
    const int row0 = trow * RPT;
    const int block_row = blockIdx.x * BM;

    float acc[RPT][4];
#pragma unroll
    for (int r = 0; r < RPT; r++)
#pragma unroll
        for (int c = 0; c < 4; c++) acc[r][c] = 0.0f;

    for (int kk = 0; kk < K; kk += BK) {
        {
            int r = tid >> 2, kq = tid & 3;
            int rg = block_row + r;
            float4 a = make_float4(0.f, 0.f, 0.f, 0.f);
            if (rg < M) a = *(const float4*)&A[(size_t)rg * K + kk + kq * 4];
            As[(kq * 4 + 0) * BM + r] = a.x;
            As[(kq * 4 + 1) * BM + r] = a.y;
            As[(kq * 4 + 2) * BM + r] = a.z;
            As[(kq * 4 + 3) * BM + r] = a.w;
        }
        {
            constexpr int F4 = BK * BN / 4;
#pragma unroll
            for (int f = tid; f < F4; f += 256) {
                int kq = f / (BN / 4), n4 = f % (BN / 4);
                *(float4*)&Bs[kq * BN + n4 * 4] =
                    *(const float4*)&B[(size_t)(kk + kq) * BN + n4 * 4];
            }
        }
        __syncthreads();
#pragma unroll
        for (int k = 0; k < BK; k++) {
            float4 b = *(const float4*)&Bs[k * BN + col0];
#pragma unroll
            for (int r = 0; r < RPT; r += 4) {
                float4 a = *(const float4*)&As[k * BM + row0 + r];
                acc[r + 0][0] += a.x * b.x; acc[r + 0][1] += a.x * b.y;
                acc[r + 0][2] += a.x * b.z; acc[r + 0][3] += a.x * b.w;
                acc[r + 1][0] += a.y * b.x; acc[r + 1][1] += a.y * b.y;
                acc[r + 1][2] += a.y * b.z; acc[r + 1][3] += a.y * b.w;
                acc[r + 2][0] += a.z * b.x; acc[r + 2][1] += a.z * b.y;
                acc[r + 2][2] += a.z * b.z; acc[r + 2][3] += a.z * b.w;
                acc[r + 3][0] += a.w * b.x; acc[r + 3][1] += a.w * b.y;
                acc[r + 3][2] += a.w * b.z; acc[r + 3][3] += a.w * b.w;
            }
        }
        __syncthreads();
    }

#pragma unroll
    for (int r = 0; r < RPT; r++) {
        int rg = block_row + row0 + r;
        if (rg < M) {
            float s = scale[rg];
            float4 v = make_float4(acc[r][0] * s, acc[r][1] * s,
                                   acc[r][2] * s, acc[r][3] * s);
            *(float4*)&C[(size_t)rg * BN + col0] = v;
        }
    }
}

// ---------------- CSR gather-sum aggregation + fused epilogue ----------------
// One wave per dst node. Lanes own feature dims. out = relu?(sum * norm[n] + bias)
template <int D, bool RELU>
__global__ __launch_bounds__(256) void gather_kernel(
    const float* __restrict__ hs, const int* __restrict__ eidx,
    const int* __restrict__ row_ofs, const float* __restrict__ norm,
    const float* __restrict__ bias, float* __restrict__ out, int n) {
    int wave = (blockIdx.x * blockDim.x + threadIdx.x) >> 6;
    int lane = threadIdx.x & 63;
    if (wave >= n) return;
    int beg = row_ofs[wave];
    int end = row_ofs[wave + 1];
    float sc = norm[wave];

    if (D == 128) {
        const float2* h2 = (const float2*)hs;
        float2 acc = make_float2(0.f, 0.f);
        int e = beg;
        for (; e + 1 < end; e += 2) {
            int s0 = eidx[e], s1 = eidx[e + 1];
            float2 v0 = h2[(size_t)s0 * 64 + lane];
            float2 v1 = h2[(size_t)s1 * 64 + lane];
            acc.x += v0.x + v1.x;
            acc.y += v0.y + v1.y;
        }
        if (e < end) {
            float2 v = h2[(size_t)eidx[e] * 64 + lane];
            acc.x += v.x;
            acc.y += v.y;
        }
        float2 b = ((const float2*)bias)[lane];
        float2 r = make_float2(acc.x * sc + b.x, acc.y * sc + b.y);
        if (RELU) { r.x = fmaxf(r.x, 0.f); r.y = fmaxf(r.y, 0.f); }
        ((float2*)out)[(size_t)wave * 64 + lane] = r;
    } else {  // D == 64
        float acc = 0.f;
        int e = beg;
        for (; e + 1 < end; e += 2) {
            int s0 = eidx[e], s1 = eidx[e + 1];
            acc += hs[(size_t)s0 * 64 + lane] + hs[(size_t)s1 * 64 + lane];
        }
        if (e < end) acc += hs[(size_t)eidx[e] * 64 + lane];
        float r = acc * sc + bias[lane];
        if (RELU) r = fmaxf(r, 0.f);
        out[(size_t)wave * 64 + lane] = r;
    }
}

extern "C" void kernel_launch(void* const* d_in, const int* in_sizes, int n_in,
                              void* d_out, int out_size, void* d_ws, size_t ws_size,
                              hipStream_t stream) {
    const float* x  = (const float*)d_in[0];   // [50000,256]
    const float* W1 = (const float*)d_in[1];   // [256,128]
    const float* b1 = (const float*)d_in[2];   // [128]
    const float* W2 = (const float*)d_in[3];   // [128,64]
    const float* b2 = (const float*)d_in[4];   // [64]
    const int* src  = (const int*)d_in[5];     // [800000]
    const int* dst  = (const int*)d_in[6];     // [800000]
    float* out = (float*)d_out;                // [50000,64]
    char* ws = (char*)d_ws;

    const int NB = (NN + 255) / 256;  // 196 scan blocks

    // ws layout (4-byte units)
    int*   cnt_src  = (int*)(ws);                       // 50176
    int*   cnt_dst  = (int*)(ws + 4 * 50176);           // 50176
    float* norm_src = (float*)(ws + 4 * 100352);        // 50176
    float* norm_dst = (float*)(ws + 4 * 150528);        // 50176
    int*   row_ofs  = (int*)(ws + 4 * 200704);          // 50432 (need 50001)
    int*   cursor   = (int*)(ws + 4 * 251136);          // 50176
    int*   blk_sum  = (int*)(ws + 4 * 301312);          // 256
    int*   blk_ofs  = (int*)(ws + 4 * 301568);          // 256
    int*   eidx     = (int*)(ws + 4 * 301824);          // 800000
    float* hs1      = (float*)(ws + 4 * 1101824);       // [50000,128]; reused as hs2
    float* h1       = (float*)(ws + 4 * 7501824);       // [50000,128]
    float* hs2      = hs1;                              // [50000,64] fits
    // total ≈ 55.6 MB

    hipMemsetAsync(cnt_src, 0, 2 * 50176 * sizeof(int), stream);  // both cnt arrays

    hist_kernel<<<1024, 256, 0, stream>>>(src, dst, cnt_src, cnt_dst, NE);
    norm_kernel<<<NB, 256, 0, stream>>>(cnt_src, cnt_dst, norm_src, norm_dst, NN);
    scanA_kernel<<<NB, 256, 0, stream>>>(cnt_dst, row_ofs, blk_sum, NN);
    scanB_kernel<<<1, 256, 0, stream>>>(blk_sum, blk_ofs, NB);
    scanC_kernel<<<NB, 256, 0, stream>>>(row_ofs, blk_ofs, cursor, NN);
    fill_kernel<<<1024, 256, 0, stream>>>(src, dst, cursor, eidx, NE);

    // layer 1: hs1 = (x @ W1) * norm_src ; h1 = relu(gather(hs1)*norm_dst + b1)
    gemm_scale_kernel<128, 256><<<(NN + 63) / 64, 256, 0, stream>>>(x, W1, norm_src, hs1, NN);
    gather_kernel<128, true><<<(NN + 3) / 4, 256, 0, stream>>>(
        hs1, eidx, row_ofs, norm_dst, b1, h1, NN);

    // layer 2: hs2 = (h1 @ W2) * norm_src ; out = gather(hs2)*norm_dst + b2
    gemm_scale_kernel<64, 128><<<(NN + 63) / 64, 256, 0, stream>>>(h1, W2, norm_src, hs2, NN);
    gather_kernel<64, false><<<(NN + 3) / 4, 256, 0, stream>>>(
        hs2, eidx, row_ofs, norm_dst, b2, out, NN);
}

// Round 4
// 399.841 us; speedup vs baseline: 5.7483x; 1.0264x over previous
//
#include <hip/hip_runtime.h>

#define NN 50000
#define NE 800000
#define NREP 8
#define REPSTR 51200
// dims: IN=256, HID=128, OUT=64

// ---------------- CSR build ----------------

// 8-way replicated histograms: rep[r*REPSTR + node], r = blockIdx&7.
__global__ void hist_kernel(const int* __restrict__ src, const int* __restrict__ dst,
                            int* __restrict__ rep_src, int* __restrict__ rep_dst, int E) {
    int r = blockIdx.x & (NREP - 1);
    int* rs = rep_src + r * REPSTR;
    int* rd = rep_dst + r * REPSTR;
    int stride = gridDim.x * blockDim.x;
    for (int i = blockIdx.x * blockDim.x + threadIdx.x; i < E; i += stride) {
        atomicAdd(&rs[src[i]], 1);
        atomicAdd(&rd[dst[i]], 1);
    }
}

// Sum replicas -> norms (+ cnt_dst total for the scan).
__global__ __launch_bounds__(256) void reduce_norm_kernel(
    const int* __restrict__ rep_src, const int* __restrict__ rep_dst,
    float* __restrict__ ns, float* __restrict__ nd, int* __restrict__ cnt_dst, int n) {
    int i = blockIdx.x * 256 + threadIdx.x;
    if (i >= n) return;
    int s = 0, d = 0;
#pragma unroll
    for (int r = 0; r < NREP; r++) {
        s += rep_src[r * REPSTR + i];
        d += rep_dst[r * REPSTR + i];
    }
    ns[i] = rsqrtf(fmaxf((float)s, 1.0f));
    nd[i] = rsqrtf(fmaxf((float)d, 1.0f));
    cnt_dst[i] = d;
}

// 3-phase scan: A) per-block exclusive scan + block sums, B) scan block sums,
// C) add block offsets -> row_ofs, cursor.
__global__ __launch_bounds__(256) void scanA_kernel(const int* __restrict__ cnt,
                                                    int* __restrict__ pref,
                                                    int* __restrict__ blk_sum, int n) {
    __shared__ int lds[256];
    int i = blockIdx.x * 256 + threadIdx.x;
    int v = (i < n) ? cnt[i] : 0;
    lds[threadIdx.x] = v;
    __syncthreads();
    for (int ofs = 1; ofs < 256; ofs <<= 1) {
        int t = (threadIdx.x >= ofs) ? lds[threadIdx.x - ofs] : 0;
        __syncthreads();
        lds[threadIdx.x] += t;
        __syncthreads();
    }
    if (i < n) pref[i] = lds[threadIdx.x] - v;  // exclusive
    if (threadIdx.x == 255) blk_sum[blockIdx.x] = lds[255];
}

__global__ __launch_bounds__(256) void scanB_kernel(const int* __restrict__ blk_sum,
                                                    int* __restrict__ blk_ofs, int nb) {
    __shared__ int lds[256];
    int v = (threadIdx.x < nb) ? blk_sum[threadIdx.x] : 0;
    lds[threadIdx.x] = v;
    __syncthreads();
    for (int ofs = 1; ofs < 256; ofs <<= 1) {
        int t = (threadIdx.x >= ofs) ? lds[threadIdx.x - ofs] : 0;
        __syncthreads();
        lds[threadIdx.x] += t;
        __syncthreads();
    }
    if (threadIdx.x < nb) blk_ofs[threadIdx.x] = lds[threadIdx.x] - v;
}

__global__ __launch_bounds__(256) void scanC_kernel(int* __restrict__ row_ofs,
                                                    const int* __restrict__ blk_ofs,
                                                    int* __restrict__ cursor, int n) {
    int i = blockIdx.x * 256 + threadIdx.x;
    if (i < n) {
        int r = row_ofs[i] + blk_ofs[blockIdx.x];
        row_ofs[i] = r;
        cursor[i] = r;
    }
    if (i == 0) row_ofs[n] = NE;  // every edge lands in some row
}

__global__ void fill_kernel(const int* __restrict__ src, const int* __restrict__ dst,
                            int* __restrict__ cursor, int* __restrict__ eidx, int E) {
    int stride = gridDim.x * blockDim.x;
    for (int i = blockIdx.x * blockDim.x + threadIdx.x; i < E; i += stride) {
        int pos = atomicAdd(&cursor[dst[i]], 1);
        eidx[pos] = src[i];
    }
}

// ---------------- GEMM with row-scale epilogue ----------------
// C[M x BN] = (A[M x K] @ B[K x BN]) * scale[row]
// BM=64, BK=16, 256 threads; As padded stride 68 (bank-conflict-free);
// software-pipelined: next tile prefetched to registers during compute.
template <int BN, int K>
__global__ __launch_bounds__(256) void gemm_scale_kernel(
    const float* __restrict__ A, const float* __restrict__ B,
    const float* __restrict__ scale, float* __restrict__ C, int M) {
    constexpr int BM = 64, BK = 16;
    constexpr int ASTR = BM + 4;   // 68: A-write bank pattern becomes 2-way (free)
    constexpr int CT = BN / 4;
    constexpr int RT = 256 / CT;
    constexpr int RPT = BM / RT;
    constexpr int BF4 = (BK * BN / 4) / 256;  // B-tile float4s per thread (2 or 1)

    __shared__ float As[BK * ASTR];
    __shared__ float Bs[BK * BN];

    const int tid = threadIdx.x;
    const int tcol = tid % CT;
    const int trow = tid / CT;
    const int col0 = tcol * 4;
    const int row0 = trow * RPT;
    const int block_row = blockIdx.x * BM;

    // A staging: lane -> (row ar, k-quad akq); coalesced 4 rows x 64B
    const int ar = tid >> 2, akq = tid & 3;
    const int arg = block_row + ar;
    const bool a_ok = arg < M;
    const float* Aptr = a_ok ? &A[(size_t)arg * K + akq * 4] : A;

    float acc[RPT][4];
#pragma unroll
    for (int r = 0; r < RPT; r++)
#pragma unroll
        for (int c = 0; c < 4; c++) acc[r][c] = 0.0f;

    // prefetch tile 0
    float4 aPf = a_ok ? *(const float4*)Aptr : make_float4(0.f, 0.f, 0.f, 0.f);
    float4 bPf[BF4];
#pragma unroll
    for (int f = 0; f < BF4; f++) {
        int ff = tid + 256 * f;
        int kq = ff / (BN / 4), n4 = ff % (BN / 4);
        bPf[f] = *(const float4*)&B[(size_t)kq * BN + n4 * 4];
    }

    for (int kk = 0; kk < K; kk += BK) {
        // store prefetched tile to LDS
        As[(akq * 4 + 0) * ASTR + ar] = aPf.x;
        As[(akq * 4 + 1) * ASTR + ar] = aPf.y;
        As[(akq * 4 + 2) * ASTR + ar] = aPf.z;
        As[(akq * 4 + 3) * ASTR + ar] = aPf.w;
#pragma unroll
        for (int f = 0; f < BF4; f++) {
            int ff = tid + 256 * f;
            int kq = ff / (BN / 4), n4 = ff % (BN / 4);
            *(float4*)&Bs[kq * BN + n4 * 4] = bPf[f];
        }
        __syncthreads();

        // prefetch next tile (overlaps with compute below)
        if (kk + BK < K) {
            aPf = a_ok ? *(const float4*)(Aptr + kk + BK)
                       : make_float4(0.f, 0.f, 0.f, 0.f);
#pragma unroll
            for (int f = 0; f < BF4; f++) {
                int ff = tid + 256 * f;
                int kq = ff / (BN / 4), n4 = ff % (BN / 4);
                bPf[f] = *(const float4*)&B[(size_t)(kk + BK + kq) * BN + n4 * 4];
            }
        }

#pragma unroll
        for (int k = 0; k < BK; k++) {
            float4 b = *(const float4*)&Bs[k * BN + col0];
#pragma unroll
            for (int r = 0; r < RPT; r += 4) {
                float4 a = *(const float4*)&As[k * ASTR + row0 + r];
                acc[r + 0][0] += a.x * b.x; acc[r + 0][1] += a.x * b.y;
                acc[r + 0][2] += a.x * b.z; acc[r + 0][3] += a.x * b.w;
                acc[r + 1][0] += a.y * b.x; acc[r + 1][1] += a.y * b.y;
                acc[r + 1][2] += a.y * b.z; acc[r + 1][3] += a.y * b.w;
                acc[r + 2][0] += a.z * b.x; acc[r + 2][1] += a.z * b.y;
                acc[r + 2][2] += a.z * b.z; acc[r + 2][3] += a.z * b.w;
                acc[r + 3][0] += a.w * b.x; acc[r + 3][1] += a.w * b.y;
                acc[r + 3][2] += a.w * b.z; acc[r + 3][3] += a.w * b.w;
            }
        }
        __syncthreads();
    }

#pragma unroll
    for (int r = 0; r < RPT; r++) {
        int rg = block_row + row0 + r;
        if (rg < M) {
            float s = scale[rg];
            float4 v = make_float4(acc[r][0] * s, acc[r][1] * s,
                                   acc[r][2] * s, acc[r][3] * s);
            *(float4*)&C[(size_t)rg * BN + col0] = v;
        }
    }
}

// ---------------- CSR gather-sum aggregation + fused epilogue ----------------
// One wave per dst node. Lanes own feature dims. out = relu?(sum * norm[n] + bias)
template <int D, bool RELU>
__global__ __launch_bounds__(256) void gather_kernel(
    const float* __restrict__ hs, const int* __restrict__ eidx,
    const int* __restrict__ row_ofs, const float* __restrict__ norm,
    const float* __restrict__ bias, float* __restrict__ out, int n) {
    int wave = (blockIdx.x * blockDim.x + threadIdx.x) >> 6;
    int lane = threadIdx.x & 63;
    if (wave >= n) return;
    int beg = row_ofs[wave];
    int end = row_ofs[wave + 1];
    float sc = norm[wave];

    if (D == 128) {
        const float2* h2 = (const float2*)hs;
        float2 acc = make_float2(0.f, 0.f);
        int e = beg;
        for (; e + 1 < end; e += 2) {
            int s0 = eidx[e], s1 = eidx[e + 1];
            float2 v0 = h2[(size_t)s0 * 64 + lane];
            float2 v1 = h2[(size_t)s1 * 64 + lane];
            acc.x += v0.x + v1.x;
            acc.y += v0.y + v1.y;
        }
        if (e < end) {
            float2 v = h2[(size_t)eidx[e] * 64 + lane];
            acc.x += v.x;
            acc.y += v.y;
        }
        float2 b = ((const float2*)bias)[lane];
        float2 r = make_float2(acc.x * sc + b.x, acc.y * sc + b.y);
        if (RELU) { r.x = fmaxf(r.x, 0.f); r.y = fmaxf(r.y, 0.f); }
        ((float2*)out)[(size_t)wave * 64 + lane] = r;
    } else {  // D == 64
        float acc = 0.f;
        int e = beg;
        for (; e + 1 < end; e += 2) {
            int s0 = eidx[e], s1 = eidx[e + 1];
            acc += hs[(size_t)s0 * 64 + lane] + hs[(size_t)s1 * 64 + lane];
        }
        if (e < end) acc += hs[(size_t)eidx[e] * 64 + lane];
        float r = acc * sc + bias[lane];
        if (RELU) r = fmaxf(r, 0.f);
        out[(size_t)wave * 64 + lane] = r;
    }
}

extern "C" void kernel_launch(void* const* d_in, const int* in_sizes, int n_in,
                              void* d_out, int out_size, void* d_ws, size_t ws_size,
                              hipStream_t stream) {
    const float* x  = (const float*)d_in[0];   // [50000,256]
    const float* W1 = (const float*)d_in[1];   // [256,128]
    const float* b1 = (const float*)d_in[2];   // [128]
    const float* W2 = (const float*)d_in[3];   // [128,64]
    const float* b2 = (const float*)d_in[4];   // [64]
    const int* src  = (const int*)d_in[5];     // [800000]
    const int* dst  = (const int*)d_in[6];     // [800000]
    float* out = (float*)d_out;                // [50000,64]
    char* ws = (char*)d_ws;

    const int NB = (NN + 255) / 256;   // 196 blocks over nodes
    const int EB = (NE + 255) / 256;   // 3125 blocks over edges

    // ws layout (4-byte units)
    float* norm_src = (float*)(ws);                     // 50176
    float* norm_dst = (float*)(ws + 4 * 50176);         // 50176
    int*   cnt_dst  = (int*)(ws + 4 * 100352);          // 50176
    int*   row_ofs  = (int*)(ws + 4 * 150528);          // 50432 (need 50001)
    int*   cursor   = (int*)(ws + 4 * 200960);          // 50176
    int*   blk_sum  = (int*)(ws + 4 * 251136);          // 256
    int*   blk_ofs  = (int*)(ws + 4 * 251392);          // 256
    int*   eidx     = (int*)(ws + 4 * 251648);          // 800000
    float* hs1      = (float*)(ws + 4 * 1051648);       // [50000,128]; reused as hs2
    float* h1       = (float*)(ws + 4 * 7451648);       // [50000,128]
    float* hs2      = hs1;                              // [50000,64] fits
    // total 13,851,648 * 4B ≈ 55.4 MB

    // replica histograms overlay h1 (dead until gather1 writes it)
    int* rep_src = (int*)h1;                            // NREP*REPSTR = 409600
    int* rep_dst = rep_src + NREP * REPSTR;             // 409600

    hipMemsetAsync(rep_src, 0, 2 * NREP * REPSTR * sizeof(int), stream);

    hist_kernel<<<EB, 256, 0, stream>>>(src, dst, rep_src, rep_dst, NE);
    reduce_norm_kernel<<<NB, 256, 0, stream>>>(rep_src, rep_dst, norm_src, norm_dst,
                                               cnt_dst, NN);
    scanA_kernel<<<NB, 256, 0, stream>>>(cnt_dst, row_ofs, blk_sum, NN);
    scanB_kernel<<<1, 256, 0, stream>>>(blk_sum, blk_ofs, NB);
    scanC_kernel<<<NB, 256, 0, stream>>>(row_ofs, blk_ofs, cursor, NN);
    fill_kernel<<<EB, 256, 0, stream>>>(src, dst, cursor, eidx, NE);

    // layer 1: hs1 = (x @ W1) * norm_src ; h1 = relu(gather(hs1)*norm_dst + b1)
    gemm_scale_kernel<128, 256><<<(NN + 63) / 64, 256, 0, stream>>>(x, W1, norm_src, hs1, NN);
    gather_kernel<128, true><<<(NN + 3) / 4, 256, 0, stream>>>(
        hs1, eidx, row_ofs, norm_dst, b1, h1, NN);

    // layer 2: hs2 = (h1 @ W2) * norm_src ; out = gather(hs2)*norm_dst + b2
    gemm_scale_kernel<64, 128><<<(NN + 63) / 64, 256, 0, stream>>>(h1, W2, norm_src, hs2, NN);
    gather_kernel<64, false><<<(NN + 3) / 4, 256, 0, stream>>>(
        hs2, eidx, row_ofs, norm_dst, b2, out, NN);
}

// Round 5
// 363.156 us; speedup vs baseline: 6.3290x; 1.1010x over previous
//
#include <hip/hip_runtime.h>

#define NN 50000
#define NE 800000
#define NREP 8
#define REPSTR 51200
// dims: IN=256, HID=128, OUT=64

typedef __attribute__((ext_vector_type(8))) short bf16x8;
typedef __attribute__((ext_vector_type(4))) float f32x4;

__device__ __forceinline__ float u2f(unsigned u) { return __uint_as_float(u); }
__device__ __forceinline__ unsigned f2u(float f) { return __float_as_uint(f); }

// ---------------- CSR build ----------------

__global__ void hist_kernel(const int* __restrict__ src, const int* __restrict__ dst,
                            int* __restrict__ rep_src, int* __restrict__ rep_dst, int E) {
    int r = blockIdx.x & (NREP - 1);
    int* rs = rep_src + r * REPSTR;
    int* rd = rep_dst + r * REPSTR;
    int stride = gridDim.x * blockDim.x;
    for (int i = blockIdx.x * blockDim.x + threadIdx.x; i < E; i += stride) {
        atomicAdd(&rs[src[i]], 1);
        atomicAdd(&rd[dst[i]], 1);
    }
}

__global__ __launch_bounds__(256) void reduce_norm_kernel(
    const int* __restrict__ rep_src, const int* __restrict__ rep_dst,
    float* __restrict__ ns, float* __restrict__ nd, int* __restrict__ cnt_dst, int n) {
    int i = blockIdx.x * 256 + threadIdx.x;
    if (i >= n) return;
    int s = 0, d = 0;
#pragma unroll
    for (int r = 0; r < NREP; r++) {
        s += rep_src[r * REPSTR + i];
        d += rep_dst[r * REPSTR + i];
    }
    ns[i] = rsqrtf(fmaxf((float)s, 1.0f));
    nd[i] = rsqrtf(fmaxf((float)d, 1.0f));
    cnt_dst[i] = d;
}

__global__ __launch_bounds__(256) void scanA_kernel(const int* __restrict__ cnt,
                                                    int* __restrict__ pref,
                                                    int* __restrict__ blk_sum, int n) {
    __shared__ int lds[256];
    int i = blockIdx.x * 256 + threadIdx.x;
    int v = (i < n) ? cnt[i] : 0;
    lds[threadIdx.x] = v;
    __syncthreads();
    for (int ofs = 1; ofs < 256; ofs <<= 1) {
        int t = (threadIdx.x >= ofs) ? lds[threadIdx.x - ofs] : 0;
        __syncthreads();
        lds[threadIdx.x] += t;
        __syncthreads();
    }
    if (i < n) pref[i] = lds[threadIdx.x] - v;
    if (threadIdx.x == 255) blk_sum[blockIdx.x] = lds[255];
}

__global__ __launch_bounds__(256) void scanB_kernel(const int* __restrict__ blk_sum,
                                                    int* __restrict__ blk_ofs, int nb) {
    __shared__ int lds[256];
    int v = (threadIdx.x < nb) ? blk_sum[threadIdx.x] : 0;
    lds[threadIdx.x] = v;
    __syncthreads();
    for (int ofs = 1; ofs < 256; ofs <<= 1) {
        int t = (threadIdx.x >= ofs) ? lds[threadIdx.x - ofs] : 0;
        __syncthreads();
        lds[threadIdx.x] += t;
        __syncthreads();
    }
    if (threadIdx.x < nb) blk_ofs[threadIdx.x] = lds[threadIdx.x] - v;
}

__global__ __launch_bounds__(256) void scanC_kernel(int* __restrict__ row_ofs,
                                                    const int* __restrict__ blk_ofs,
                                                    int* __restrict__ cursor, int n) {
    int i = blockIdx.x * 256 + threadIdx.x;
    if (i < n) {
        int r = row_ofs[i] + blk_ofs[blockIdx.x];
        row_ofs[i] = r;
        cursor[i] = r;
    }
    if (i == 0) row_ofs[n] = NE;
}

__global__ void fill_kernel(const int* __restrict__ src, const int* __restrict__ dst,
                            int* __restrict__ cursor, int* __restrict__ eidx, int E) {
    int stride = gridDim.x * blockDim.x;
    for (int i = blockIdx.x * blockDim.x + threadIdx.x; i < E; i += stride) {
        int pos = atomicAdd(&cursor[dst[i]], 1);
        eidx[pos] = src[i];
    }
}

// ---------------- W pre-transform: fp32 [K][N] -> fragment-ordered bf16 hi/lo ----
// Frag order: f = (((n>>4)*(K/8) + (k>>3))*16 + (n&15))*8 + (k&7)
// => lane L's b-frag for (n-tile t, k-chunk base fb) is 16 contiguous bytes at
//    ((t*(K/8)+fb)*16 + (L&15))*8 shorts — perfectly coalesced dwordx4.
template <int K, int N>
__global__ __launch_bounds__(256) void wtrans_kernel(const float* __restrict__ W,
                                                     unsigned short* __restrict__ Wh,
                                                     unsigned short* __restrict__ Wl) {
    int i = blockIdx.x * 256 + threadIdx.x;
    if (i >= K * N) return;
    int k = i / N, n = i % N;
    int f = (((n >> 4) * (K / 8) + (k >> 3)) * 16 + (n & 15)) * 8 + (k & 7);
    float w = W[i];
    unsigned u = f2u(w);
    float lo = w - u2f(u & 0xffff0000u);
    Wh[f] = (unsigned short)(u >> 16);
    Wl[f] = (unsigned short)(f2u(lo) >> 16);
}

// ---------------- split-bf16 MFMA GEMM ----------------
// out[M x N](bf16) = (A[M x K](fp32) @ W[K x N]) * scale[row]
// via Ah*Bh + Ah*Bl + Al*Bh (error ~2^-16 relative: fp32-class).
// 4 waves/block, wave owns 16 rows x N. No LDS; A read once, W from L2.
template <int N, int K>
__global__ __launch_bounds__(256) void gemm_mfma_kernel(
    const float* __restrict__ A, const unsigned short* __restrict__ Wh,
    const unsigned short* __restrict__ Wl, const float* __restrict__ scale,
    unsigned short* __restrict__ out, int M) {
    constexpr int NT = N / 16;   // n-tiles per wave
    constexpr int KC = K / 32;   // k-chunks
    const int wave = threadIdx.x >> 6;
    const int lane = threadIdx.x & 63;
    const int ln = lane & 15;
    const int qk = lane >> 4;
    const int m0 = blockIdx.x * 64 + wave * 16;
    const int mA = m0 + ln;
    const bool a_ok = mA < M;
    // A-frag: lane reads A[m0+ln][c*32 + qk*8 .. +7] (row 128B segments, coalesced)
    const float* Arow = A + (size_t)(a_ok ? mA : (M - 1)) * K + qk * 8;
    const bf16x8* BH = (const bf16x8*)Wh;
    const bf16x8* BL = (const bf16x8*)Wl;

    f32x4 acc[NT];
#pragma unroll
    for (int t = 0; t < NT; t++) acc[t] = (f32x4){0.f, 0.f, 0.f, 0.f};

#pragma unroll 2
    for (int c = 0; c < KC; ++c) {
        float4 a0 = *(const float4*)(Arow + c * 32);
        float4 a1 = *(const float4*)(Arow + c * 32 + 4);
        if (!a_ok) {
            a0 = make_float4(0.f, 0.f, 0.f, 0.f);
            a1 = make_float4(0.f, 0.f, 0.f, 0.f);
        }
        float av[8] = {a0.x, a0.y, a0.z, a0.w, a1.x, a1.y, a1.z, a1.w};
        bf16x8 ah, al;
#pragma unroll
        for (int j = 0; j < 8; ++j) {
            unsigned u = f2u(av[j]);
            float lo = av[j] - u2f(u & 0xffff0000u);
            ah[j] = (short)(u >> 16);
            al[j] = (short)(f2u(lo) >> 16);
        }
        const int fb = c * 4 + qk;
#pragma unroll
        for (int t = 0; t < NT; ++t) {
            bf16x8 bh = BH[(t * (K / 8) + fb) * 16 + ln];
            bf16x8 bl = BL[(t * (K / 8) + fb) * 16 + ln];
            acc[t] = __builtin_amdgcn_mfma_f32_16x16x32_bf16(ah, bh, acc[t], 0, 0, 0);
            acc[t] = __builtin_amdgcn_mfma_f32_16x16x32_bf16(ah, bl, acc[t], 0, 0, 0);
            acc[t] = __builtin_amdgcn_mfma_f32_16x16x32_bf16(al, bh, acc[t], 0, 0, 0);
        }
    }

    // C/D layout: row = m0 + qk*4 + reg, col = t*16 + ln  [m89-verified]
    float sc[4];
    int rows[4];
#pragma unroll
    for (int r = 0; r < 4; ++r) {
        rows[r] = m0 + qk * 4 + r;
        sc[r] = (rows[r] < M) ? scale[rows[r]] : 0.f;
    }
#pragma unroll
    for (int t = 0; t < NT; ++t) {
#pragma unroll
        for (int r = 0; r < 4; ++r) {
            if (rows[r] < M) {
                float v = acc[t][r] * sc[r];
                unsigned u = f2u(v);
                unsigned rnd = ((u >> 16) & 1u) + 0x7fffu;  // RNE to bf16
                out[(size_t)rows[r] * N + t * 16 + ln] = (unsigned short)((u + rnd) >> 16);
            }
        }
    }
}

// ---------------- CSR gather-sum (bf16 input) + fused epilogue ----------------
// One wave per dst node; lanes own feature dims; fp32 accumulate/output.
template <bool RELU>
__global__ __launch_bounds__(256) void gather128_kernel(
    const unsigned* __restrict__ hs,  // bf16[128] rows = 64 uints
    const int* __restrict__ eidx, const int* __restrict__ row_ofs,
    const float* __restrict__ norm, const float* __restrict__ bias,
    float* __restrict__ out, int n) {
    int wave = (blockIdx.x * blockDim.x + threadIdx.x) >> 6;
    int lane = threadIdx.x & 63;
    if (wave >= n) return;
    int beg = row_ofs[wave], end = row_ofs[wave + 1];
    float sc = norm[wave];
    float ax = 0.f, ay = 0.f;
    int e = beg;
    for (; e + 1 < end; e += 2) {
        unsigned u0 = hs[(size_t)eidx[e] * 64 + lane];
        unsigned u1 = hs[(size_t)eidx[e + 1] * 64 + lane];
        ax += u2f(u0 << 16) + u2f(u1 << 16);
        ay += u2f(u0 & 0xffff0000u) + u2f(u1 & 0xffff0000u);
    }
    if (e < end) {
        unsigned u0 = hs[(size_t)eidx[e] * 64 + lane];
        ax += u2f(u0 << 16);
        ay += u2f(u0 & 0xffff0000u);
    }
    float2 b = ((const float2*)bias)[lane];
    float rx = ax * sc + b.x;
    float ry = ay * sc + b.y;
    if (RELU) { rx = fmaxf(rx, 0.f); ry = fmaxf(ry, 0.f); }
    ((float2*)out)[(size_t)wave * 64 + lane] = make_float2(rx, ry);
}

__global__ __launch_bounds__(256) void gather64_kernel(
    const unsigned short* __restrict__ hs,  // bf16[64] rows
    const int* __restrict__ eidx, const int* __restrict__ row_ofs,
    const float* __restrict__ norm, const float* __restrict__ bias,
    float* __restrict__ out, int n) {
    int wave = (blockIdx.x * blockDim.x + threadIdx.x) >> 6;
    int lane = threadIdx.x & 63;
    if (wave >= n) return;
    int beg = row_ofs[wave], end = row_ofs[wave + 1];
    float sc = norm[wave];
    float acc = 0.f;
    int e = beg;
    for (; e + 1 < end; e += 2) {
        acc += u2f(((unsigned)hs[(size_t)eidx[e] * 64 + lane]) << 16) +
               u2f(((unsigned)hs[(size_t)eidx[e + 1] * 64 + lane]) << 16);
    }
    if (e < end) acc += u2f(((unsigned)hs[(size_t)eidx[e] * 64 + lane]) << 16);
    out[(size_t)wave * 64 + lane] = acc * sc + bias[lane];
}

extern "C" void kernel_launch(void* const* d_in, const int* in_sizes, int n_in,
                              void* d_out, int out_size, void* d_ws, size_t ws_size,
                              hipStream_t stream) {
    const float* x  = (const float*)d_in[0];   // [50000,256]
    const float* W1 = (const float*)d_in[1];   // [256,128]
    const float* b1 = (const float*)d_in[2];   // [128]
    const float* W2 = (const float*)d_in[3];   // [128,64]
    const float* b2 = (const float*)d_in[4];   // [64]
    const int* src  = (const int*)d_in[5];     // [800000]
    const int* dst  = (const int*)d_in[6];     // [800000]
    float* out = (float*)d_out;                // [50000,64] fp32
    char* ws = (char*)d_ws;

    const int NB = (NN + 255) / 256;   // 196
    const int EB = (NE + 255) / 256;   // 3125

    // ws layout (dword offsets)
    float* norm_src = (float*)(ws);                       // 50176
    float* norm_dst = (float*)(ws + 4 * 50176);           // 50176
    int*   cnt_dst  = (int*)(ws + 4 * 100352);            // 50176
    int*   row_ofs  = (int*)(ws + 4 * 150528);            // 50432
    int*   cursor   = (int*)(ws + 4 * 200960);            // 50176
    int*   blk_sum  = (int*)(ws + 4 * 251136);            // 256
    int*   blk_ofs  = (int*)(ws + 4 * 251392);            // 256
    int*   eidx     = (int*)(ws + 4 * 251648);            // 800000
    unsigned short* Wh1 = (unsigned short*)(ws + 4 * 1051648);  // 32768 us (16384 dw)
    unsigned short* Wl1 = (unsigned short*)(ws + 4 * 1068032);  // 16384 dw
    unsigned short* Wh2 = (unsigned short*)(ws + 4 * 1084416);  // 4096 dw
    unsigned short* Wl2 = (unsigned short*)(ws + 4 * 1088512);  // 4096 dw
    unsigned short* hs1 = (unsigned short*)(ws + 4 * 1092608);  // bf16 [50000,128]
    unsigned short* hs2 = (unsigned short*)(ws + 4 * 4292608);  // bf16 [50000,64]
    float* h1           = (float*)(ws + 4 * 5892608);           // fp32 [50000,128]
    // end 12,292,608 dwords ≈ 49.2 MB

    // replica histograms overlay h1 (dead until gather1)
    int* rep_src = (int*)h1;                 // NREP*REPSTR
    int* rep_dst = rep_src + NREP * REPSTR;

    hipMemsetAsync(rep_src, 0, 2 * NREP * REPSTR * sizeof(int), stream);

    hist_kernel<<<EB, 256, 0, stream>>>(src, dst, rep_src, rep_dst, NE);
    reduce_norm_kernel<<<NB, 256, 0, stream>>>(rep_src, rep_dst, norm_src, norm_dst,
                                               cnt_dst, NN);
    scanA_kernel<<<NB, 256, 0, stream>>>(cnt_dst, row_ofs, blk_sum, NN);
    scanB_kernel<<<1, 256, 0, stream>>>(blk_sum, blk_ofs, NB);
    scanC_kernel<<<NB, 256, 0, stream>>>(row_ofs, blk_ofs, cursor, NN);
    fill_kernel<<<EB, 256, 0, stream>>>(src, dst, cursor, eidx, NE);

    wtrans_kernel<256, 128><<<128, 256, 0, stream>>>(W1, Wh1, Wl1);
    wtrans_kernel<128, 64><<<32, 256, 0, stream>>>(W2, Wh2, Wl2);

    // layer 1
    gemm_mfma_kernel<128, 256><<<(NN + 63) / 64, 256, 0, stream>>>(
        x, Wh1, Wl1, norm_src, hs1, NN);
    gather128_kernel<true><<<(NN + 3) / 4, 256, 0, stream>>>(
        (const unsigned*)hs1, eidx, row_ofs, norm_dst, b1, h1, NN);

    // layer 2
    gemm_mfma_kernel<64, 128><<<(NN + 63) / 64, 256, 0, stream>>>(
        h1, Wh2, Wl2, norm_src, hs2, NN);
    gather64_kernel<<<(NN + 3) / 4, 256, 0, stream>>>(
        hs2, eidx, row_ofs, norm_dst, b2, out, NN);
}

// Round 6
// 352.578 us; speedup vs baseline: 6.5189x; 1.0300x over previous
//
#include <hip/hip_runtime.h>

#define NN 50000
#define NE 800000
#define NREP 8
#define REPSTR 51200
// dims: IN=256, HID=128, OUT=64

typedef __attribute__((ext_vector_type(8))) short bf16x8;
typedef __attribute__((ext_vector_type(4))) float f32x4;

__device__ __forceinline__ float u2f(unsigned u) { return __uint_as_float(u); }
__device__ __forceinline__ unsigned f2u(float f) { return __float_as_uint(f); }

// ---------------- W pre-transform: fp32 [K][N] -> fragment-ordered bf16 hi/lo ----
// f = (((n>>4)*(K/8) + (k>>3))*16 + (n&15))*8 + (k&7)
template <int K, int N>
__global__ __launch_bounds__(256) void wtrans_kernel(const float* __restrict__ W,
                                                     unsigned short* __restrict__ Wh,
                                                     unsigned short* __restrict__ Wl) {
    int i = blockIdx.x * 256 + threadIdx.x;
    if (i >= K * N) return;
    int k = i / N, n = i % N;
    int f = (((n >> 4) * (K / 8) + (k >> 3)) * 16 + (n & 15)) * 8 + (k & 7);
    float w = W[i];
    unsigned u = f2u(w);
    float lo = w - u2f(u & 0xffff0000u);
    Wh[f] = (unsigned short)(u >> 16);
    Wl[f] = (unsigned short)(f2u(lo) >> 16);
}

// ---------------- split-bf16 MFMA GEMM body (no scale; unscaled bf16 out) ------
// out[M x N](bf16) = A[M x K](fp32) @ W[K x N] via Ah*Bh + Ah*Bl + Al*Bh.
template <int N, int K>
__device__ __forceinline__ void gemm_body(
    const float* __restrict__ A, const unsigned short* __restrict__ Wh,
    const unsigned short* __restrict__ Wl, unsigned short* __restrict__ out, int M) {
    constexpr int NT = N / 16;
    constexpr int KC = K / 32;
    const int wave = threadIdx.x >> 6;
    const int lane = threadIdx.x & 63;
    const int ln = lane & 15;
    const int qk = lane >> 4;
    const int m0 = blockIdx.x * 64 + wave * 16;
    const int mA = m0 + ln;
    const bool a_ok = mA < M;
    const float* Arow = A + (size_t)(a_ok ? mA : (M - 1)) * K + qk * 8;
    const bf16x8* BH = (const bf16x8*)Wh;
    const bf16x8* BL = (const bf16x8*)Wl;

    f32x4 acc[NT];
#pragma unroll
    for (int t = 0; t < NT; t++) acc[t] = (f32x4){0.f, 0.f, 0.f, 0.f};

#pragma unroll 2
    for (int c = 0; c < KC; ++c) {
        float4 a0 = *(const float4*)(Arow + c * 32);
        float4 a1 = *(const float4*)(Arow + c * 32 + 4);
        if (!a_ok) {
            a0 = make_float4(0.f, 0.f, 0.f, 0.f);
            a1 = make_float4(0.f, 0.f, 0.f, 0.f);
        }
        float av[8] = {a0.x, a0.y, a0.z, a0.w, a1.x, a1.y, a1.z, a1.w};
        bf16x8 ah, al;
#pragma unroll
        for (int j = 0; j < 8; ++j) {
            unsigned u = f2u(av[j]);
            float lo = av[j] - u2f(u & 0xffff0000u);
            ah[j] = (short)(u >> 16);
            al[j] = (short)(f2u(lo) >> 16);
        }
        const int fb = c * 4 + qk;
#pragma unroll
        for (int t = 0; t < NT; ++t) {
            bf16x8 bh = BH[(t * (K / 8) + fb) * 16 + ln];
            bf16x8 bl = BL[(t * (K / 8) + fb) * 16 + ln];
            acc[t] = __builtin_amdgcn_mfma_f32_16x16x32_bf16(ah, bh, acc[t], 0, 0, 0);
            acc[t] = __builtin_amdgcn_mfma_f32_16x16x32_bf16(ah, bl, acc[t], 0, 0, 0);
            acc[t] = __builtin_amdgcn_mfma_f32_16x16x32_bf16(al, bh, acc[t], 0, 0, 0);
        }
    }

    // C/D: row = m0 + qk*4 + reg, col = t*16 + ln
#pragma unroll
    for (int t = 0; t < NT; ++t) {
#pragma unroll
        for (int r = 0; r < 4; ++r) {
            int row = m0 + qk * 4 + r;
            if (row < M) {
                unsigned u = f2u(acc[t][r]);
                unsigned rnd = ((u >> 16) & 1u) + 0x7fffu;  // RNE to bf16
                out[(size_t)row * N + t * 16 + ln] = (unsigned short)((u + rnd) >> 16);
            }
        }
    }
}

// Fused: degree histograms (fire-and-forget atomics) + layer-1 GEMM.
// Atomics issue first and drain under the MFMA compute.
__global__ __launch_bounds__(256) void gemm1_hist_kernel(
    const float* __restrict__ A, const unsigned short* __restrict__ Wh,
    const unsigned short* __restrict__ Wl, unsigned short* __restrict__ out, int M,
    const int* __restrict__ src, const int* __restrict__ dst,
    int* __restrict__ rep_src, int* __restrict__ rep_dst, int E) {
    {
        int r = blockIdx.x & (NREP - 1);
        int* rs = rep_src + r * REPSTR;
        int* rd = rep_dst + r * REPSTR;
        int stride = gridDim.x * blockDim.x;
        for (int i = blockIdx.x * blockDim.x + threadIdx.x; i < E; i += stride) {
            atomicAdd(&rs[src[i]], 1);
            atomicAdd(&rd[dst[i]], 1);
        }
    }
    gemm_body<128, 256>(A, Wh, Wl, out, M);
}

__global__ __launch_bounds__(256) void gemm2_kernel(
    const float* __restrict__ A, const unsigned short* __restrict__ Wh,
    const unsigned short* __restrict__ Wl, unsigned short* __restrict__ out, int M) {
    gemm_body<64, 128>(A, Wh, Wl, out, M);
}

// ---------------- CSR build (post-hist) ----------------

// Fused: reduce replicas -> norms, then block-level exclusive scan of cnt_dst.
__global__ __launch_bounds__(256) void norm_scanA_kernel(
    const int* __restrict__ rep_src, const int* __restrict__ rep_dst,
    float* __restrict__ ns, float* __restrict__ nd,
    int* __restrict__ pref, int* __restrict__ blk_sum, int n) {
    __shared__ int lds[256];
    int i = blockIdx.x * 256 + threadIdx.x;
    int d = 0;
    if (i < n) {
        int s = 0;
#pragma unroll
        for (int r = 0; r < NREP; r++) {
            s += rep_src[r * REPSTR + i];
            d += rep_dst[r * REPSTR + i];
        }
        ns[i] = rsqrtf(fmaxf((float)s, 1.0f));
        nd[i] = rsqrtf(fmaxf((float)d, 1.0f));
    }
    lds[threadIdx.x] = d;
    __syncthreads();
    for (int ofs = 1; ofs < 256; ofs <<= 1) {
        int t = (threadIdx.x >= ofs) ? lds[threadIdx.x - ofs] : 0;
        __syncthreads();
        lds[threadIdx.x] += t;
        __syncthreads();
    }
    if (i < n) pref[i] = lds[threadIdx.x] - d;
    if (threadIdx.x == 255) blk_sum[blockIdx.x] = lds[255];
}

__global__ __launch_bounds__(256) void scanB_kernel(const int* __restrict__ blk_sum,
                                                    int* __restrict__ blk_ofs, int nb) {
    __shared__ int lds[256];
    int v = (threadIdx.x < nb) ? blk_sum[threadIdx.x] : 0;
    lds[threadIdx.x] = v;
    __syncthreads();
    for (int ofs = 1; ofs < 256; ofs <<= 1) {
        int t = (threadIdx.x >= ofs) ? lds[threadIdx.x - ofs] : 0;
        __syncthreads();
        lds[threadIdx.x] += t;
        __syncthreads();
    }
    if (threadIdx.x < nb) blk_ofs[threadIdx.x] = lds[threadIdx.x] - v;
}

__global__ __launch_bounds__(256) void scanC_kernel(int* __restrict__ row_ofs,
                                                    const int* __restrict__ blk_ofs,
                                                    int* __restrict__ cursor, int n) {
    int i = blockIdx.x * 256 + threadIdx.x;
    if (i < n) {
        int r = row_ofs[i] + blk_ofs[blockIdx.x];
        row_ofs[i] = r;
        cursor[i] = r;
    }
    if (i == 0) row_ofs[n] = NE;
}

__global__ void fill_kernel(const int* __restrict__ src, const int* __restrict__ dst,
                            int* __restrict__ cursor, int* __restrict__ eidx, int E) {
    int stride = gridDim.x * blockDim.x;
    for (int i = blockIdx.x * blockDim.x + threadIdx.x; i < E; i += stride) {
        int pos = atomicAdd(&cursor[dst[i]], 1);
        eidx[pos] = src[i];
    }
}

// ---------------- CSR gather-sum (bf16, per-edge src-norm) + epilogue ----------
// D=128: one wave per dst node, lane owns 2 dims (uint), 2 edges per iter.
template <bool RELU>
__global__ __launch_bounds__(256) void gather128_kernel(
    const unsigned* __restrict__ hs, const int* __restrict__ eidx,
    const int* __restrict__ row_ofs, const float* __restrict__ norm_src,
    const float* __restrict__ norm_dst, const float* __restrict__ bias,
    float* __restrict__ out, int n) {
    int wave = (blockIdx.x * blockDim.x + threadIdx.x) >> 6;
    int lane = threadIdx.x & 63;
    if (wave >= n) return;
    int beg = row_ofs[wave], end = row_ofs[wave + 1];
    float sc = norm_dst[wave];
    float ax = 0.f, ay = 0.f;
    int e = beg;
    for (; e + 1 < end; e += 2) {
        int s0 = eidx[e], s1 = eidx[e + 1];
        float n0 = norm_src[s0], n1 = norm_src[s1];
        unsigned u0 = hs[(size_t)s0 * 64 + lane];
        unsigned u1 = hs[(size_t)s1 * 64 + lane];
        ax += n0 * u2f(u0 << 16) + n1 * u2f(u1 << 16);
        ay += n0 * u2f(u0 & 0xffff0000u) + n1 * u2f(u1 & 0xffff0000u);
    }
    if (e < end) {
        int s0 = eidx[e];
        float n0 = norm_src[s0];
        unsigned u0 = hs[(size_t)s0 * 64 + lane];
        ax += n0 * u2f(u0 << 16);
        ay += n0 * u2f(u0 & 0xffff0000u);
    }
    float2 b = ((const float2*)bias)[lane];
    float rx = ax * sc + b.x;
    float ry = ay * sc + b.y;
    if (RELU) { rx = fmaxf(rx, 0.f); ry = fmaxf(ry, 0.f); }
    ((float2*)out)[(size_t)wave * 64 + lane] = make_float2(rx, ry);
}

// D=64: one wave per dst node; half-wave per edge (lane loads uint = 2 dims,
// 32 lanes cover the 128B row); cross-half combine via shfl_xor(32).
__global__ __launch_bounds__(256) void gather64_kernel(
    const unsigned* __restrict__ hs,  // bf16[64] rows = 32 uints
    const int* __restrict__ eidx, const int* __restrict__ row_ofs,
    const float* __restrict__ norm_src, const float* __restrict__ norm_dst,
    const float* __restrict__ bias, float* __restrict__ out, int n) {
    int wave = (blockIdx.x * blockDim.x + threadIdx.x) >> 6;
    int lane = threadIdx.x & 63;
    if (wave >= n) return;
    int beg = row_ofs[wave], end = row_ofs[wave + 1];
    int half = lane >> 5;      // 0 or 1
    int dim = lane & 31;
    float ax = 0.f, ay = 0.f;
    for (int e = beg + half; e < end; e += 2) {
        int s = eidx[e];
        float ns = norm_src[s];
        unsigned u = hs[(size_t)s * 32 + dim];
        ax += ns * u2f(u << 16);
        ay += ns * u2f(u & 0xffff0000u);
    }
    ax += __shfl_xor(ax, 32);
    ay += __shfl_xor(ay, 32);
    if (half == 0) {
        float sc = norm_dst[wave];
        float2 b = ((const float2*)bias)[dim];
        ((float2*)out)[(size_t)wave * 32 + dim] =
            make_float2(ax * sc + b.x, ay * sc + b.y);
    }
}

extern "C" void kernel_launch(void* const* d_in, const int* in_sizes, int n_in,
                              void* d_out, int out_size, void* d_ws, size_t ws_size,
                              hipStream_t stream) {
    const float* x  = (const float*)d_in[0];   // [50000,256]
    const float* W1 = (const float*)d_in[1];   // [256,128]
    const float* b1 = (const float*)d_in[2];   // [128]
    const float* W2 = (const float*)d_in[3];   // [128,64]
    const float* b2 = (const float*)d_in[4];   // [64]
    const int* src  = (const int*)d_in[5];     // [800000]
    const int* dst  = (const int*)d_in[6];     // [800000]
    float* out = (float*)d_out;                // [50000,64] fp32
    char* ws = (char*)d_ws;

    const int NB = (NN + 255) / 256;   // 196
    const int EB = (NE + 255) / 256;   // 3125
    const int GB = (NN + 63) / 64;     // 782 gemm blocks

    // ws layout (dword offsets)
    float* norm_src = (float*)(ws);                       // 50176
    float* norm_dst = (float*)(ws + 4 * 50176);           // 50176
    int*   row_ofs  = (int*)(ws + 4 * 150528);            // 50432
    int*   cursor   = (int*)(ws + 4 * 200960);            // 50176
    int*   blk_sum  = (int*)(ws + 4 * 251136);            // 256
    int*   blk_ofs  = (int*)(ws + 4 * 251392);            // 256
    int*   eidx     = (int*)(ws + 4 * 251648);            // 800000
    unsigned short* Wh1 = (unsigned short*)(ws + 4 * 1051648);  // 16384 dw
    unsigned short* Wl1 = (unsigned short*)(ws + 4 * 1068032);  // 16384 dw
    unsigned short* Wh2 = (unsigned short*)(ws + 4 * 1084416);  // 4096 dw
    unsigned short* Wl2 = (unsigned short*)(ws + 4 * 1088512);  // 4096 dw
    unsigned short* hs1 = (unsigned short*)(ws + 4 * 1092608);  // bf16 [50000,128]
    unsigned short* hs2 = (unsigned short*)(ws + 4 * 4292608);  // bf16 [50000,64]
    float* h1           = (float*)(ws + 4 * 5892608);           // fp32 [50000,128]
    // end 12,292,608 dwords ≈ 49.2 MB

    // replica histograms overlay h1 (dead until gather1)
    int* rep_src = (int*)h1;
    int* rep_dst = rep_src + NREP * REPSTR;

    hipMemsetAsync(rep_src, 0, 2 * NREP * REPSTR * sizeof(int), stream);

    wtrans_kernel<256, 128><<<128, 256, 0, stream>>>(W1, Wh1, Wl1);
    wtrans_kernel<128, 64><<<32, 256, 0, stream>>>(W2, Wh2, Wl2);

    // fused: histograms (atomics drain under MFMA) + layer-1 GEMM (unscaled)
    gemm1_hist_kernel<<<GB, 256, 0, stream>>>(x, Wh1, Wl1, hs1, NN,
                                              src, dst, rep_src, rep_dst, NE);

    norm_scanA_kernel<<<NB, 256, 0, stream>>>(rep_src, rep_dst, norm_src, norm_dst,
                                              row_ofs, blk_sum, NN);
    scanB_kernel<<<1, 256, 0, stream>>>(blk_sum, blk_ofs, NB);
    scanC_kernel<<<NB, 256, 0, stream>>>(row_ofs, blk_ofs, cursor, NN);
    fill_kernel<<<EB, 256, 0, stream>>>(src, dst, cursor, eidx, NE);

    gather128_kernel<true><<<(NN + 3) / 4, 256, 0, stream>>>(
        (const unsigned*)hs1, eidx, row_ofs, norm_src, norm_dst, b1, h1, NN);

    gemm2_kernel<<<GB, 256, 0, stream>>>(h1, Wh2, Wl2, hs2, NN);

    gather64_kernel<<<(NN + 3) / 4, 256, 0, stream>>>(
        (const unsigned*)hs2, eidx, row_ofs, norm_src, norm_dst, b2, out, NN);
}

// Round 7
// 322.894 us; speedup vs baseline: 7.1182x; 1.0919x over previous
//
#include <hip/hip_runtime.h>

#define NN 50000
#define NE 800000
#define NREP 8
#define REPSTR 51200
#define HB 2048   // hist-specialized blocks in the fused kernel
// dims: IN=256, HID=128, OUT=64

typedef __attribute__((ext_vector_type(8))) short bf16x8;
typedef __attribute__((ext_vector_type(4))) float f32x4;

__device__ __forceinline__ float u2f(unsigned u) { return __uint_as_float(u); }
__device__ __forceinline__ unsigned f2u(float f) { return __float_as_uint(f); }

// ---------------- W pre-transform: fp32 [K][N] -> fragment-ordered bf16 hi/lo ----
// f = (((n>>4)*(K/8) + (k>>3))*16 + (n&15))*8 + (k&7)
template <int K, int N>
__global__ __launch_bounds__(256) void wtrans_kernel(const float* __restrict__ W,
                                                     unsigned short* __restrict__ Wh,
                                                     unsigned short* __restrict__ Wl) {
    int i = blockIdx.x * 256 + threadIdx.x;
    if (i >= K * N) return;
    int k = i / N, n = i % N;
    int f = (((n >> 4) * (K / 8) + (k >> 3)) * 16 + (n & 15)) * 8 + (k & 7);
    float w = W[i];
    unsigned u = f2u(w);
    float lo = w - u2f(u & 0xffff0000u);
    Wh[f] = (unsigned short)(u >> 16);
    Wl[f] = (unsigned short)(f2u(lo) >> 16);
}

// ---------------- split-bf16 MFMA GEMM body (unscaled bf16 out) ------
// out[M x N](bf16) = A[M x K](fp32) @ W[K x N] via Ah*Bh + Ah*Bl + Al*Bh.
template <int N, int K>
__device__ __forceinline__ void gemm_body(
    int bid, const float* __restrict__ A, const unsigned short* __restrict__ Wh,
    const unsigned short* __restrict__ Wl, unsigned short* __restrict__ out, int M) {
    constexpr int NT = N / 16;
    constexpr int KC = K / 32;
    const int wave = threadIdx.x >> 6;
    const int lane = threadIdx.x & 63;
    const int ln = lane & 15;
    const int qk = lane >> 4;
    const int m0 = bid * 64 + wave * 16;
    const int mA = m0 + ln;
    const bool a_ok = mA < M;
    const float* Arow = A + (size_t)(a_ok ? mA : (M - 1)) * K + qk * 8;
    const bf16x8* BH = (const bf16x8*)Wh;
    const bf16x8* BL = (const bf16x8*)Wl;

    f32x4 acc[NT];
#pragma unroll
    for (int t = 0; t < NT; t++) acc[t] = (f32x4){0.f, 0.f, 0.f, 0.f};

#pragma unroll 2
    for (int c = 0; c < KC; ++c) {
        float4 a0 = *(const float4*)(Arow + c * 32);
        float4 a1 = *(const float4*)(Arow + c * 32 + 4);
        if (!a_ok) {
            a0 = make_float4(0.f, 0.f, 0.f, 0.f);
            a1 = make_float4(0.f, 0.f, 0.f, 0.f);
        }
        float av[8] = {a0.x, a0.y, a0.z, a0.w, a1.x, a1.y, a1.z, a1.w};
        bf16x8 ah, al;
#pragma unroll
        for (int j = 0; j < 8; ++j) {
            unsigned u = f2u(av[j]);
            float lo = av[j] - u2f(u & 0xffff0000u);
            ah[j] = (short)(u >> 16);
            al[j] = (short)(f2u(lo) >> 16);
        }
        const int fb = c * 4 + qk;
#pragma unroll
        for (int t = 0; t < NT; ++t) {
            bf16x8 bh = BH[(t * (K / 8) + fb) * 16 + ln];
            bf16x8 bl = BL[(t * (K / 8) + fb) * 16 + ln];
            acc[t] = __builtin_amdgcn_mfma_f32_16x16x32_bf16(ah, bh, acc[t], 0, 0, 0);
            acc[t] = __builtin_amdgcn_mfma_f32_16x16x32_bf16(ah, bl, acc[t], 0, 0, 0);
            acc[t] = __builtin_amdgcn_mfma_f32_16x16x32_bf16(al, bh, acc[t], 0, 0, 0);
        }
    }

    // C/D: row = m0 + qk*4 + reg, col = t*16 + ln
#pragma unroll
    for (int t = 0; t < NT; ++t) {
#pragma unroll
        for (int r = 0; r < 4; ++r) {
            int row = m0 + qk * 4 + r;
            if (row < M) {
                unsigned u = f2u(acc[t][r]);
                unsigned rnd = ((u >> 16) & 1u) + 0x7fffu;  // RNE to bf16
                out[(size_t)row * N + t * 16 + ln] = (unsigned short)((u + rnd) >> 16);
            }
        }
    }
}

// Block-specialized: blocks [0,HB) = degree histograms (pure atomics);
// blocks [HB, HB+GB) = layer-1 GEMM. Atomic waves and MFMA waves co-reside
// per CU and overlap (separate pipes).
__global__ __launch_bounds__(256) void gemm1_hist_kernel(
    const float* __restrict__ A, const unsigned short* __restrict__ Wh,
    const unsigned short* __restrict__ Wl, unsigned short* __restrict__ out, int M,
    const int* __restrict__ src, const int* __restrict__ dst,
    int* __restrict__ rep_src, int* __restrict__ rep_dst, int E) {
    if (blockIdx.x < HB) {
        int r = blockIdx.x & (NREP - 1);
        int* rs = rep_src + r * REPSTR;
        int* rd = rep_dst + r * REPSTR;
        int stride = HB * 256;
        for (int i = blockIdx.x * 256 + threadIdx.x; i < E; i += stride) {
            atomicAdd(&rs[src[i]], 1);
            atomicAdd(&rd[dst[i]], 1);
        }
    } else {
        gemm_body<128, 256>(blockIdx.x - HB, A, Wh, Wl, out, M);
    }
}

__global__ __launch_bounds__(256) void gemm2_kernel(
    const float* __restrict__ A, const unsigned short* __restrict__ Wh,
    const unsigned short* __restrict__ Wl, unsigned short* __restrict__ out, int M) {
    gemm_body<64, 128>(blockIdx.x, A, Wh, Wl, out, M);
}

// ---------------- CSR build (post-hist) ----------------

__global__ __launch_bounds__(256) void norm_scanA_kernel(
    const int* __restrict__ rep_src, const int* __restrict__ rep_dst,
    float* __restrict__ ns, float* __restrict__ nd,
    int* __restrict__ pref, int* __restrict__ blk_sum, int n) {
    __shared__ int lds[256];
    int i = blockIdx.x * 256 + threadIdx.x;
    int d = 0;
    if (i < n) {
        int s = 0;
#pragma unroll
        for (int r = 0; r < NREP; r++) {
            s += rep_src[r * REPSTR + i];
            d += rep_dst[r * REPSTR + i];
        }
        ns[i] = rsqrtf(fmaxf((float)s, 1.0f));
        nd[i] = rsqrtf(fmaxf((float)d, 1.0f));
    }
    lds[threadIdx.x] = d;
    __syncthreads();
    for (int ofs = 1; ofs < 256; ofs <<= 1) {
        int t = (threadIdx.x >= ofs) ? lds[threadIdx.x - ofs] : 0;
        __syncthreads();
        lds[threadIdx.x] += t;
        __syncthreads();
    }
    if (i < n) pref[i] = lds[threadIdx.x] - d;
    if (threadIdx.x == 255) blk_sum[blockIdx.x] = lds[255];
}

__global__ __launch_bounds__(256) void scanB_kernel(const int* __restrict__ blk_sum,
                                                    int* __restrict__ blk_ofs, int nb) {
    __shared__ int lds[256];
    int v = (threadIdx.x < nb) ? blk_sum[threadIdx.x] : 0;
    lds[threadIdx.x] = v;
    __syncthreads();
    for (int ofs = 1; ofs < 256; ofs <<= 1) {
        int t = (threadIdx.x >= ofs) ? lds[threadIdx.x - ofs] : 0;
        __syncthreads();
        lds[threadIdx.x] += t;
        __syncthreads();
    }
    if (threadIdx.x < nb) blk_ofs[threadIdx.x] = lds[threadIdx.x] - v;
}

__global__ __launch_bounds__(256) void scanC_kernel(int* __restrict__ row_ofs,
                                                    const int* __restrict__ blk_ofs,
                                                    int* __restrict__ cursor, int n) {
    int i = blockIdx.x * 256 + threadIdx.x;
    if (i < n) {
        int r = row_ofs[i] + blk_ofs[blockIdx.x];
        row_ofs[i] = r;
        cursor[i] = r;
    }
    if (i == 0) row_ofs[n] = NE;
}

__global__ void fill_kernel(const int* __restrict__ src, const int* __restrict__ dst,
                            int* __restrict__ cursor, int* __restrict__ eidx, int E) {
    int stride = gridDim.x * blockDim.x;
    for (int i = blockIdx.x * blockDim.x + threadIdx.x; i < E; i += stride) {
        int pos = atomicAdd(&cursor[dst[i]], 1);
        eidx[pos] = src[i];
    }
}

// ---------------- CSR gather-sum (bf16, per-edge src-norm) + epilogue ----------
// D=128: one wave per dst node, lane owns 2 dims; 4 independent edges in flight.
template <bool RELU>
__global__ __launch_bounds__(256) void gather128_kernel(
    const unsigned* __restrict__ hs, const int* __restrict__ eidx,
    const int* __restrict__ row_ofs, const float* __restrict__ norm_src,
    const float* __restrict__ norm_dst, const float* __restrict__ bias,
    float* __restrict__ out, int n) {
    int wave = (blockIdx.x * blockDim.x + threadIdx.x) >> 6;
    int lane = threadIdx.x & 63;
    if (wave >= n) return;
    int beg = row_ofs[wave], end = row_ofs[wave + 1];
    float sc = norm_dst[wave];
    float ax = 0.f, ay = 0.f;
    int e = beg;
    for (; e + 3 < end; e += 4) {
        int s0 = eidx[e], s1 = eidx[e + 1], s2 = eidx[e + 2], s3 = eidx[e + 3];
        float n0 = norm_src[s0], n1 = norm_src[s1];
        float n2 = norm_src[s2], n3 = norm_src[s3];
        unsigned u0 = hs[(size_t)s0 * 64 + lane];
        unsigned u1 = hs[(size_t)s1 * 64 + lane];
        unsigned u2 = hs[(size_t)s2 * 64 + lane];
        unsigned u3 = hs[(size_t)s3 * 64 + lane];
        ax += n0 * u2f(u0 << 16) + n1 * u2f(u1 << 16) +
              n2 * u2f(u2 << 16) + n3 * u2f(u3 << 16);
        ay += n0 * u2f(u0 & 0xffff0000u) + n1 * u2f(u1 & 0xffff0000u) +
              n2 * u2f(u2 & 0xffff0000u) + n3 * u2f(u3 & 0xffff0000u);
    }
    for (; e < end; ++e) {
        int s0 = eidx[e];
        float n0 = norm_src[s0];
        unsigned u0 = hs[(size_t)s0 * 64 + lane];
        ax += n0 * u2f(u0 << 16);
        ay += n0 * u2f(u0 & 0xffff0000u);
    }
    float2 b = ((const float2*)bias)[lane];
    float rx = ax * sc + b.x;
    float ry = ay * sc + b.y;
    if (RELU) { rx = fmaxf(rx, 0.f); ry = fmaxf(ry, 0.f); }
    ((float2*)out)[(size_t)wave * 64 + lane] = make_float2(rx, ry);
}

// D=64: one wave per dst node; half-wave per edge (lane loads uint = 2 dims);
// 2 edges in flight per half; cross-half combine via shfl_xor(32).
__global__ __launch_bounds__(256) void gather64_kernel(
    const unsigned* __restrict__ hs,  // bf16[64] rows = 32 uints
    const int* __restrict__ eidx, const int* __restrict__ row_ofs,
    const float* __restrict__ norm_src, const float* __restrict__ norm_dst,
    const float* __restrict__ bias, float* __restrict__ out, int n) {
    int wave = (blockIdx.x * blockDim.x + threadIdx.x) >> 6;
    int lane = threadIdx.x & 63;
    if (wave >= n) return;
    int beg = row_ofs[wave], end = row_ofs[wave + 1];
    int half = lane >> 5;      // 0 or 1
    int dim = lane & 31;
    float ax = 0.f, ay = 0.f;
    int e = beg + half;
    for (; e + 2 < end; e += 4) {  // this half handles e and e+2
        int s0 = eidx[e], s1 = eidx[e + 2];
        float n0 = norm_src[s0], n1 = norm_src[s1];
        unsigned u0 = hs[(size_t)s0 * 32 + dim];
        unsigned u1 = hs[(size_t)s1 * 32 + dim];
        ax += n0 * u2f(u0 << 16) + n1 * u2f(u1 << 16);
        ay += n0 * u2f(u0 & 0xffff0000u) + n1 * u2f(u1 & 0xffff0000u);
    }
    if (e < end) {
        int s0 = eidx[e];
        float n0 = norm_src[s0];
        unsigned u0 = hs[(size_t)s0 * 32 + dim];
        ax += n0 * u2f(u0 << 16);
        ay += n0 * u2f(u0 & 0xffff0000u);
    }
    ax += __shfl_xor(ax, 32);
    ay += __shfl_xor(ay, 32);
    if (half == 0) {
        float sc = norm_dst[wave];
        float2 b = ((const float2*)bias)[dim];
        ((float2*)out)[(size_t)wave * 32 + dim] =
            make_float2(ax * sc + b.x, ay * sc + b.y);
    }
}

extern "C" void kernel_launch(void* const* d_in, const int* in_sizes, int n_in,
                              void* d_out, int out_size, void* d_ws, size_t ws_size,
                              hipStream_t stream) {
    const float* x  = (const float*)d_in[0];   // [50000,256]
    const float* W1 = (const float*)d_in[1];   // [256,128]
    const float* b1 = (const float*)d_in[2];   // [128]
    const float* W2 = (const float*)d_in[3];   // [128,64]
    const float* b2 = (const float*)d_in[4];   // [64]
    const int* src  = (const int*)d_in[5];     // [800000]
    const int* dst  = (const int*)d_in[6];     // [800000]
    float* out = (float*)d_out;                // [50000,64] fp32
    char* ws = (char*)d_ws;

    const int NB = (NN + 255) / 256;   // 196
    const int EB = (NE + 255) / 256;   // 3125
    const int GB = (NN + 63) / 64;     // 782 gemm blocks

    // ws layout (dword offsets)
    float* norm_src = (float*)(ws);                       // 50176
    float* norm_dst = (float*)(ws + 4 * 50176);           // 50176
    int*   row_ofs  = (int*)(ws + 4 * 150528);            // 50432
    int*   cursor   = (int*)(ws + 4 * 200960);            // 50176
    int*   blk_sum  = (int*)(ws + 4 * 251136);            // 256
    int*   blk_ofs  = (int*)(ws + 4 * 251392);            // 256
    int*   eidx     = (int*)(ws + 4 * 251648);            // 800000
    unsigned short* Wh1 = (unsigned short*)(ws + 4 * 1051648);  // 16384 dw
    unsigned short* Wl1 = (unsigned short*)(ws + 4 * 1068032);  // 16384 dw
    unsigned short* Wh2 = (unsigned short*)(ws + 4 * 1084416);  // 4096 dw
    unsigned short* Wl2 = (unsigned short*)(ws + 4 * 1088512);  // 4096 dw
    unsigned short* hs1 = (unsigned short*)(ws + 4 * 1092608);  // bf16 [50000,128]
    unsigned short* hs2 = (unsigned short*)(ws + 4 * 4292608);  // bf16 [50000,64]
    float* h1           = (float*)(ws + 4 * 5892608);           // fp32 [50000,128]
    // end 12,292,608 dwords ≈ 49.2 MB

    // replica histograms overlay h1 (dead until gather1)
    int* rep_src = (int*)h1;
    int* rep_dst = rep_src + NREP * REPSTR;

    hipMemsetAsync(rep_src, 0, 2 * NREP * REPSTR * sizeof(int), stream);

    wtrans_kernel<256, 128><<<128, 256, 0, stream>>>(W1, Wh1, Wl1);
    wtrans_kernel<128, 64><<<32, 256, 0, stream>>>(W2, Wh2, Wl2);

    // block-specialized: hist atomics overlap layer-1 MFMA GEMM
    gemm1_hist_kernel<<<HB + GB, 256, 0, stream>>>(x, Wh1, Wl1, hs1, NN,
                                                   src, dst, rep_src, rep_dst, NE);

    norm_scanA_kernel<<<NB, 256, 0, stream>>>(rep_src, rep_dst, norm_src, norm_dst,
                                              row_ofs, blk_sum, NN);
    scanB_kernel<<<1, 256, 0, stream>>>(blk_sum, blk_ofs, NB);
    scanC_kernel<<<NB, 256, 0, stream>>>(row_ofs, blk_ofs, cursor, NN);
    fill_kernel<<<EB, 256, 0, stream>>>(src, dst, cursor, eidx, NE);

    gather128_kernel<true><<<(NN + 3) / 4, 256, 0, stream>>>(
        (const unsigned*)hs1, eidx, row_ofs, norm_src, norm_dst, b1, h1, NN);

    gemm2_kernel<<<GB, 256, 0, stream>>>(h1, Wh2, Wl2, hs2, NN);

    gather64_kernel<<<(NN + 3) / 4, 256, 0, stream>>>(
        (const unsigned*)hs2, eidx, row_ofs, norm_src, norm_dst, b2, out, NN);
}

// Round 8
// 294.242 us; speedup vs baseline: 7.8113x; 1.0974x over previous
//
#include <hip/hip_runtime.h>

#define NN 50000
#define NE 800000
// dims: IN=256, HID=128, OUT=64
#define NPART 8      // node partitions for LDS hist (6272 nodes, 25 KB each)
#define PSZ 6272     // NPART*PSZ = 50176 >= NN
#define NSLICE 32    // edge slices
#define ESL 25000    // NE / NSLICE
#define HBK 512      // hist blocks = 2 sides * NPART * NSLICE
#define GB 782       // gemm-1 blocks = ceil(NN/64)
#define TOTB (HBK + GB)

typedef __attribute__((ext_vector_type(8))) short bf16x8;
typedef __attribute__((ext_vector_type(4))) float f32x4;

__device__ __forceinline__ float u2f(unsigned u) { return __uint_as_float(u); }
__device__ __forceinline__ unsigned f2u(float f) { return __float_as_uint(f); }

// ---------------- W pre-transform: fp32 [K][N] -> fragment-ordered bf16 hi/lo ----
// f = (((n>>4)*(K/8) + (k>>3))*16 + (n&15))*8 + (k&7)
template <int K, int N>
__global__ __launch_bounds__(256) void wtrans_kernel(const float* __restrict__ W,
                                                     unsigned short* __restrict__ Wh,
                                                     unsigned short* __restrict__ Wl) {
    int i = blockIdx.x * 256 + threadIdx.x;
    if (i >= K * N) return;
    int k = i / N, n = i % N;
    int f = (((n >> 4) * (K / 8) + (k >> 3)) * 16 + (n & 15)) * 8 + (k & 7);
    float w = W[i];
    unsigned u = f2u(w);
    float lo = w - u2f(u & 0xffff0000u);
    Wh[f] = (unsigned short)(u >> 16);
    Wl[f] = (unsigned short)(f2u(lo) >> 16);
}

// ---------------- split-bf16 MFMA GEMM body (unscaled bf16 out) ------
// out[M x N](bf16) = A[M x K](fp32) @ W[K x N] via Ah*Bh + Ah*Bl + Al*Bh.
template <int N, int K>
__device__ __forceinline__ void gemm_body(
    int bid, const float* __restrict__ A, const unsigned short* __restrict__ Wh,
    const unsigned short* __restrict__ Wl, unsigned short* __restrict__ out, int M) {
    constexpr int NT = N / 16;
    constexpr int KC = K / 32;
    const int wave = threadIdx.x >> 6;
    const int lane = threadIdx.x & 63;
    const int ln = lane & 15;
    const int qk = lane >> 4;
    const int m0 = bid * 64 + wave * 16;
    const int mA = m0 + ln;
    const bool a_ok = mA < M;
    const float* Arow = A + (size_t)(a_ok ? mA : (M - 1)) * K + qk * 8;
    const bf16x8* BH = (const bf16x8*)Wh;
    const bf16x8* BL = (const bf16x8*)Wl;

    f32x4 acc[NT];
#pragma unroll
    for (int t = 0; t < NT; t++) acc[t] = (f32x4){0.f, 0.f, 0.f, 0.f};

#pragma unroll 2
    for (int c = 0; c < KC; ++c) {
        float4 a0 = *(const float4*)(Arow + c * 32);
        float4 a1 = *(const float4*)(Arow + c * 32 + 4);
        if (!a_ok) {
            a0 = make_float4(0.f, 0.f, 0.f, 0.f);
            a1 = make_float4(0.f, 0.f, 0.f, 0.f);
        }
        float av[8] = {a0.x, a0.y, a0.z, a0.w, a1.x, a1.y, a1.z, a1.w};
        bf16x8 ah, al;
#pragma unroll
        for (int j = 0; j < 8; ++j) {
            unsigned u = f2u(av[j]);
            float lo = av[j] - u2f(u & 0xffff0000u);
            ah[j] = (short)(u >> 16);
            al[j] = (short)(f2u(lo) >> 16);
        }
        const int fb = c * 4 + qk;
#pragma unroll
        for (int t = 0; t < NT; ++t) {
            bf16x8 bh = BH[(t * (K / 8) + fb) * 16 + ln];
            bf16x8 bl = BL[(t * (K / 8) + fb) * 16 + ln];
            acc[t] = __builtin_amdgcn_mfma_f32_16x16x32_bf16(ah, bh, acc[t], 0, 0, 0);
            acc[t] = __builtin_amdgcn_mfma_f32_16x16x32_bf16(ah, bl, acc[t], 0, 0, 0);
            acc[t] = __builtin_amdgcn_mfma_f32_16x16x32_bf16(al, bh, acc[t], 0, 0, 0);
        }
    }

    // C/D: row = m0 + qk*4 + reg, col = t*16 + ln
#pragma unroll
    for (int t = 0; t < NT; ++t) {
#pragma unroll
        for (int r = 0; r < 4; ++r) {
            int row = m0 + qk * 4 + r;
            if (row < M) {
                unsigned u = f2u(acc[t][r]);
                unsigned rnd = ((u >> 16) & 1u) + 0x7fffu;  // RNE to bf16
                out[(size_t)row * N + t * 16 + ln] = (unsigned short)((u + rnd) >> 16);
            }
        }
    }
}

// Fused, Bresenham-interleaved: GB gemm-role blocks and HBK hist-role blocks
// alternate in dispatch order so every CU co-hosts MFMA waves and memory waves.
// Hist role: (side, partition, slice) block counts its node-partition's degrees
// in LDS (no global atomics), flushes slice-major: cnt[slice*50176 + node].
__global__ __launch_bounds__(256) void gemm1_hist_kernel(
    const float* __restrict__ A, const unsigned short* __restrict__ Wh,
    const unsigned short* __restrict__ Wl, unsigned short* __restrict__ out, int M,
    const int* __restrict__ src, const int* __restrict__ dst,
    int* __restrict__ cnt_src_sl, int* __restrict__ cnt_dst_sl) {
    __shared__ int lcnt[PSZ];
    const int bx = blockIdx.x;
    const int f0 = (int)(((long long)bx * GB) / TOTB);
    const int f1 = (int)(((long long)(bx + 1) * GB) / TOTB);
    if (f1 > f0) {
        gemm_body<128, 256>(f0, A, Wh, Wl, out, M);
        return;
    }
    const int hid = bx - f0;                 // [0, HBK)
    const int side = hid & 1;
    const int t = hid >> 1;
    const int part = t & (NPART - 1);
    const int slice = t >> 3;                // [0, NSLICE)
    const int* __restrict__ arr = side ? dst : src;
    int* __restrict__ outc = side ? cnt_dst_sl : cnt_src_sl;
    const int base = part * PSZ;

    for (int j = threadIdx.x; j < PSZ; j += 256) lcnt[j] = 0;
    __syncthreads();
    const int e0 = slice * ESL;
    for (int i = e0 + threadIdx.x; i < e0 + ESL; i += 256) {
        int v = arr[i] - base;
        if ((unsigned)v < (unsigned)PSZ) atomicAdd(&lcnt[v], 1);
    }
    __syncthreads();
    int* o = outc + slice * 50176 + base;
    for (int j = threadIdx.x; j < PSZ; j += 256) o[j] = lcnt[j];  // coalesced
}

__global__ __launch_bounds__(256) void gemm2_kernel(
    const float* __restrict__ A, const unsigned short* __restrict__ Wh,
    const unsigned short* __restrict__ Wl, unsigned short* __restrict__ out, int M) {
    gemm_body<64, 128>(blockIdx.x, A, Wh, Wl, out, M);
}

// ---------------- CSR build (post-hist) ----------------

// Sum 32 slice-replicas per side -> norms; block-level exclusive scan of dst count.
__global__ __launch_bounds__(256) void norm_scanA_kernel(
    const int* __restrict__ cs_sl, const int* __restrict__ cd_sl,
    float* __restrict__ ns, float* __restrict__ nd,
    int* __restrict__ pref, int* __restrict__ blk_sum, int n) {
    __shared__ int lds[256];
    int i = blockIdx.x * 256 + threadIdx.x;
    int d = 0;
    if (i < n) {
        int s = 0;
#pragma unroll
        for (int r = 0; r < NSLICE; r++) {
            s += cs_sl[r * 50176 + i];    // coalesced per r
            d += cd_sl[r * 50176 + i];
        }
        ns[i] = rsqrtf(fmaxf((float)s, 1.0f));
        nd[i] = rsqrtf(fmaxf((float)d, 1.0f));
    }
    lds[threadIdx.x] = d;
    __syncthreads();
    for (int ofs = 1; ofs < 256; ofs <<= 1) {
        int t = (threadIdx.x >= ofs) ? lds[threadIdx.x - ofs] : 0;
        __syncthreads();
        lds[threadIdx.x] += t;
        __syncthreads();
    }
    if (i < n) pref[i] = lds[threadIdx.x] - d;
    if (threadIdx.x == 255) blk_sum[blockIdx.x] = lds[255];
}

__global__ __launch_bounds__(256) void scanB_kernel(const int* __restrict__ blk_sum,
                                                    int* __restrict__ blk_ofs, int nb) {
    __shared__ int lds[256];
    int v = (threadIdx.x < nb) ? blk_sum[threadIdx.x] : 0;
    lds[threadIdx.x] = v;
    __syncthreads();
    for (int ofs = 1; ofs < 256; ofs <<= 1) {
        int t = (threadIdx.x >= ofs) ? lds[threadIdx.x - ofs] : 0;
        __syncthreads();
        lds[threadIdx.x] += t;
        __syncthreads();
    }
    if (threadIdx.x < nb) blk_ofs[threadIdx.x] = lds[threadIdx.x] - v;
}

__global__ __launch_bounds__(256) void scanC_kernel(int* __restrict__ row_ofs,
                                                    const int* __restrict__ blk_ofs,
                                                    int* __restrict__ cursor, int n) {
    int i = blockIdx.x * 256 + threadIdx.x;
    if (i < n) {
        int r = row_ofs[i] + blk_ofs[blockIdx.x];
        row_ofs[i] = r;
        cursor[i] = r;
    }
    if (i == 0) row_ofs[n] = NE;
}

__global__ void fill_kernel(const int* __restrict__ src, const int* __restrict__ dst,
                            int* __restrict__ cursor, int* __restrict__ eidx, int E) {
    int stride = gridDim.x * blockDim.x;
    for (int i = blockIdx.x * blockDim.x + threadIdx.x; i < E; i += stride) {
        int pos = atomicAdd(&cursor[dst[i]], 1);
        eidx[pos] = src[i];
    }
}

// ---------------- CSR gather-sum (bf16, per-edge src-norm) + epilogue ----------
// D=128: one wave per dst node, lane owns 2 dims; 4 independent edges in flight.
template <bool RELU>
__global__ __launch_bounds__(256) void gather128_kernel(
    const unsigned* __restrict__ hs, const int* __restrict__ eidx,
    const int* __restrict__ row_ofs, const float* __restrict__ norm_src,
    const float* __restrict__ norm_dst, const float* __restrict__ bias,
    float* __restrict__ out, int n) {
    int wave = (blockIdx.x * blockDim.x + threadIdx.x) >> 6;
    int lane = threadIdx.x & 63;
    if (wave >= n) return;
    int beg = row_ofs[wave], end = row_ofs[wave + 1];
    float sc = norm_dst[wave];
    float ax = 0.f, ay = 0.f;
    int e = beg;
    for (; e + 3 < end; e += 4) {
        int s0 = eidx[e], s1 = eidx[e + 1], s2 = eidx[e + 2], s3 = eidx[e + 3];
        float n0 = norm_src[s0], n1 = norm_src[s1];
        float n2 = norm_src[s2], n3 = norm_src[s3];
        unsigned u0 = hs[(size_t)s0 * 64 + lane];
        unsigned u1 = hs[(size_t)s1 * 64 + lane];
        unsigned u2 = hs[(size_t)s2 * 64 + lane];
        unsigned u3 = hs[(size_t)s3 * 64 + lane];
        ax += n0 * u2f(u0 << 16) + n1 * u2f(u1 << 16) +
              n2 * u2f(u2 << 16) + n3 * u2f(u3 << 16);
        ay += n0 * u2f(u0 & 0xffff0000u) + n1 * u2f(u1 & 0xffff0000u) +
              n2 * u2f(u2 & 0xffff0000u) + n3 * u2f(u3 & 0xffff0000u);
    }
    for (; e < end; ++e) {
        int s0 = eidx[e];
        float n0 = norm_src[s0];
        unsigned u0 = hs[(size_t)s0 * 64 + lane];
        ax += n0 * u2f(u0 << 16);
        ay += n0 * u2f(u0 & 0xffff0000u);
    }
    float2 b = ((const float2*)bias)[lane];
    float rx = ax * sc + b.x;
    float ry = ay * sc + b.y;
    if (RELU) { rx = fmaxf(rx, 0.f); ry = fmaxf(ry, 0.f); }
    ((float2*)out)[(size_t)wave * 64 + lane] = make_float2(rx, ry);
}

// D=64: one wave per dst node; half-wave per edge; 2 edges in flight per half.
__global__ __launch_bounds__(256) void gather64_kernel(
    const unsigned* __restrict__ hs,  // bf16[64] rows = 32 uints
    const int* __restrict__ eidx, const int* __restrict__ row_ofs,
    const float* __restrict__ norm_src, const float* __restrict__ norm_dst,
    const float* __restrict__ bias, float* __restrict__ out, int n) {
    int wave = (blockIdx.x * blockDim.x + threadIdx.x) >> 6;
    int lane = threadIdx.x & 63;
    if (wave >= n) return;
    int beg = row_ofs[wave], end = row_ofs[wave + 1];
    int half = lane >> 5;
    int dim = lane & 31;
    float ax = 0.f, ay = 0.f;
    int e = beg + half;
    for (; e + 2 < end; e += 4) {
        int s0 = eidx[e], s1 = eidx[e + 2];
        float n0 = norm_src[s0], n1 = norm_src[s1];
        unsigned u0 = hs[(size_t)s0 * 32 + dim];
        unsigned u1 = hs[(size_t)s1 * 32 + dim];
        ax += n0 * u2f(u0 << 16) + n1 * u2f(u1 << 16);
        ay += n0 * u2f(u0 & 0xffff0000u) + n1 * u2f(u1 & 0xffff0000u);
    }
    if (e < end) {
        int s0 = eidx[e];
        float n0 = norm_src[s0];
        unsigned u0 = hs[(size_t)s0 * 32 + dim];
        ax += n0 * u2f(u0 << 16);
        ay += n0 * u2f(u0 & 0xffff0000u);
    }
    ax += __shfl_xor(ax, 32);
    ay += __shfl_xor(ay, 32);
    if (half == 0) {
        float sc = norm_dst[wave];
        float2 b = ((const float2*)bias)[dim];
        ((float2*)out)[(size_t)wave * 32 + dim] =
            make_float2(ax * sc + b.x, ay * sc + b.y);
    }
}

extern "C" void kernel_launch(void* const* d_in, const int* in_sizes, int n_in,
                              void* d_out, int out_size, void* d_ws, size_t ws_size,
                              hipStream_t stream) {
    const float* x  = (const float*)d_in[0];   // [50000,256]
    const float* W1 = (const float*)d_in[1];   // [256,128]
    const float* b1 = (const float*)d_in[2];   // [128]
    const float* W2 = (const float*)d_in[3];   // [128,64]
    const float* b2 = (const float*)d_in[4];   // [64]
    const int* src  = (const int*)d_in[5];     // [800000]
    const int* dst  = (const int*)d_in[6];     // [800000]
    float* out = (float*)d_out;                // [50000,64] fp32
    char* ws = (char*)d_ws;

    const int NB = (NN + 255) / 256;   // 196
    const int EB = (NE + 255) / 256;   // 3125

    // ws layout (dword offsets)
    float* norm_src = (float*)(ws);                       // 50176
    float* norm_dst = (float*)(ws + 4 * 50176);           // 50176
    int*   row_ofs  = (int*)(ws + 4 * 100352);            // 50432
    int*   cursor   = (int*)(ws + 4 * 150784);            // 50176
    int*   blk_sum  = (int*)(ws + 4 * 200960);            // 256
    int*   blk_ofs  = (int*)(ws + 4 * 201216);            // 256
    int*   eidx     = (int*)(ws + 4 * 201472);            // 800000
    unsigned short* Wh1 = (unsigned short*)(ws + 4 * 1001472);  // 16384 dw
    unsigned short* Wl1 = (unsigned short*)(ws + 4 * 1017856);  // 16384 dw
    unsigned short* Wh2 = (unsigned short*)(ws + 4 * 1034240);  // 4096 dw
    unsigned short* Wl2 = (unsigned short*)(ws + 4 * 1038336);  // 4096 dw
    unsigned short* hs1 = (unsigned short*)(ws + 4 * 1042432);  // bf16 [50000,128]
    unsigned short* hs2 = (unsigned short*)(ws + 4 * 4242432);  // bf16 [50000,64]
    float* h1           = (float*)(ws + 4 * 5842432);           // fp32 [50000,128]
    // end 12,242,432 dwords ≈ 49.0 MB

    // slice-count replicas overlay h1 (dead until gather1); 2 x 1,605,632 dw
    int* cnt_src_sl = (int*)h1;
    int* cnt_dst_sl = cnt_src_sl + NSLICE * 50176;

    wtrans_kernel<256, 128><<<128, 256, 0, stream>>>(W1, Wh1, Wl1);
    wtrans_kernel<128, 64><<<32, 256, 0, stream>>>(W2, Wh2, Wl2);

    // interleaved: LDS-hist blocks + layer-1 MFMA GEMM blocks co-scheduled
    gemm1_hist_kernel<<<TOTB, 256, 0, stream>>>(x, Wh1, Wl1, hs1, NN,
                                                src, dst, cnt_src_sl, cnt_dst_sl);

    norm_scanA_kernel<<<NB, 256, 0, stream>>>(cnt_src_sl, cnt_dst_sl,
                                              norm_src, norm_dst,
                                              row_ofs, blk_sum, NN);
    scanB_kernel<<<1, 256, 0, stream>>>(blk_sum, blk_ofs, NB);
    scanC_kernel<<<NB, 256, 0, stream>>>(row_ofs, blk_ofs, cursor, NN);
    fill_kernel<<<EB, 256, 0, stream>>>(src, dst, cursor, eidx, NE);

    gather128_kernel<true><<<(NN + 3) / 4, 256, 0, stream>>>(
        (const unsigned*)hs1, eidx, row_ofs, norm_src, norm_dst, b1, h1, NN);

    gemm2_kernel<<<GB, 256, 0, stream>>>(h1, Wh2, Wl2, hs2, NN);

    gather64_kernel<<<(NN + 3) / 4, 256, 0, stream>>>(
        (const unsigned*)hs2, eidx, row_ofs, norm_src, norm_dst, b2, out, NN);
}

// Round 9
// 240.227 us; speedup vs baseline: 9.5677x; 1.2249x over previous
//
#include <hip/hip_runtime.h>

#define NN 50000
#define NE 800000
#define NPAD 50176
// dims: IN=256, HID=128, OUT=64
#define NSLICE 32
#define ESL 25000     // NE / NSLICE
#define HPN 25088     // hist nodes per part (2 parts)
#define HPW 12544     // packed words per part (49 KB LDS)
#define FPN 12544     // fill nodes per part (4 parts, 49 KB LDS)
#define GB 782        // gemm blocks = ceil(NN/64)

typedef __attribute__((ext_vector_type(8))) short bf16x8;
typedef __attribute__((ext_vector_type(4))) float f32x4;

__device__ __forceinline__ float u2f(unsigned u) { return __uint_as_float(u); }
__device__ __forceinline__ unsigned f2u(float f) { return __float_as_uint(f); }
__device__ __forceinline__ unsigned short f2bf(float f) {
    unsigned u = f2u(f);
    return (unsigned short)((u + (((u >> 16) & 1u) + 0x7fffu)) >> 16);  // RNE
}

// ---------------- W pre-transform (both weights, one launch) ----------------
// frag order: f = (((n>>4)*(K/8) + (k>>3))*16 + (n&15))*8 + (k&7)
__global__ __launch_bounds__(256) void wtrans_kernel(
    const float* __restrict__ W1, const float* __restrict__ W2,
    unsigned short* __restrict__ Wh1, unsigned short* __restrict__ Wl1,
    unsigned short* __restrict__ Wh2, unsigned short* __restrict__ Wl2) {
    int b = blockIdx.x;
    float w;
    unsigned short *ph, *pl;
    int f;
    if (b < 128) {  // W1: K=256, N=128
        int i = b * 256 + threadIdx.x;
        int k = i >> 7, n = i & 127;
        f = (((n >> 4) * 32 + (k >> 3)) * 16 + (n & 15)) * 8 + (k & 7);
        w = W1[i]; ph = Wh1; pl = Wl1;
    } else {        // W2: K=128, N=64
        int i = (b - 128) * 256 + threadIdx.x;
        int k = i >> 6, n = i & 63;
        f = (((n >> 4) * 16 + (k >> 3)) * 16 + (n & 15)) * 8 + (k & 7);
        w = W2[i]; ph = Wh2; pl = Wl2;
    }
    unsigned u = f2u(w);
    float lo = w - u2f(u & 0xffff0000u);
    ph[f] = (unsigned short)(u >> 16);
    pl[f] = (unsigned short)(f2u(lo) >> 16);
}

// ---------------- packed-ushort LDS histogram ----------------
// 128 blocks = side(2) x slice(32) x part(2). Two counters per LDS word;
// max per-slice count 25000 < 2^16 so no cross-half carry. No global atomics.
__global__ __launch_bounds__(1024) void hist_kernel(
    const int* __restrict__ src, const int* __restrict__ dst,
    unsigned* __restrict__ cnt_sl) {
    __shared__ unsigned lcnt[HPW];
    const int b = blockIdx.x;
    const int side = b & 1;
    const int slice = (b >> 1) & (NSLICE - 1);
    const int part = b >> 6;
    const int* __restrict__ arr = side ? dst : src;
    const int base = part * HPN;
    for (int j = threadIdx.x; j < HPW; j += 1024) lcnt[j] = 0;
    __syncthreads();
    const int e0 = slice * ESL;
    for (int i = e0 + threadIdx.x; i < e0 + ESL; i += 1024) {
        int v = arr[i] - base;
        if ((unsigned)v < (unsigned)HPN)
            atomicAdd(&lcnt[v >> 1], 1u << ((v & 1) * 16));
    }
    __syncthreads();
    unsigned* o = cnt_sl + (size_t)b * HPW;
    for (int j = threadIdx.x; j < HPW; j += 1024) o[j] = lcnt[j];
}

// ---------------- norms + per-slice presum + block-level scan ----------------
__global__ __launch_bounds__(256) void norm_scanA_kernel(
    const unsigned* __restrict__ cnt_sl, float* __restrict__ ns,
    float* __restrict__ nd, int* __restrict__ presum,
    int* __restrict__ pref, int* __restrict__ blk_sum, int n) {
    __shared__ int lds[256];
    int i = blockIdx.x * 256 + threadIdx.x;
    int d_total = 0;
    if (i < n) {
        int part = (i >= HPN) ? 1 : 0;
        int w = (i - part * HPN) >> 1;
        int sh = (i & 1) * 16;
        int s_total = 0;
#pragma unroll
        for (int sl = 0; sl < NSLICE; sl++) {
            int bb = part * 64 + sl * 2;
            s_total += (cnt_sl[(size_t)bb * HPW + w] >> sh) & 0xffff;
            int c = (cnt_sl[(size_t)(bb + 1) * HPW + w] >> sh) & 0xffff;
            presum[sl * NPAD + i] = d_total;
            d_total += c;
        }
        ns[i] = rsqrtf(fmaxf((float)s_total, 1.0f));
        nd[i] = rsqrtf(fmaxf((float)d_total, 1.0f));
    }
    lds[threadIdx.x] = d_total;
    __syncthreads();
    for (int ofs = 1; ofs < 256; ofs <<= 1) {
        int t = (threadIdx.x >= ofs) ? lds[threadIdx.x - ofs] : 0;
        __syncthreads();
        lds[threadIdx.x] += t;
        __syncthreads();
    }
    if (i < n) pref[i] = lds[threadIdx.x] - d_total;
    if (threadIdx.x == 255) blk_sum[blockIdx.x] = lds[255];
}

__global__ __launch_bounds__(256) void scanB_kernel(const int* __restrict__ blk_sum,
                                                    int* __restrict__ blk_ofs, int nb) {
    __shared__ int lds[256];
    int v = (threadIdx.x < nb) ? blk_sum[threadIdx.x] : 0;
    lds[threadIdx.x] = v;
    __syncthreads();
    for (int ofs = 1; ofs < 256; ofs <<= 1) {
        int t = (threadIdx.x >= ofs) ? lds[threadIdx.x - ofs] : 0;
        __syncthreads();
        lds[threadIdx.x] += t;
        __syncthreads();
    }
    if (threadIdx.x < nb) blk_ofs[threadIdx.x] = lds[threadIdx.x] - v;
}

__global__ __launch_bounds__(256) void scanC_kernel(int* __restrict__ row_ofs,
                                                    const int* __restrict__ blk_ofs, int n) {
    int i = blockIdx.x * 256 + threadIdx.x;
    if (i < n) row_ofs[i] += blk_ofs[blockIdx.x];
    if (i == 0) row_ofs[n] = NE;
}

// ---------------- atomic-free CSR fill (LDS cursors) ----------------
// 128 blocks = slice(32) x part(4). Cursor = row_ofs + presum[slice]; LDS atomics.
__global__ __launch_bounds__(1024) void fill_kernel(
    const int* __restrict__ src, const int* __restrict__ dst,
    const int* __restrict__ row_ofs, const int* __restrict__ presum,
    int* __restrict__ eidx) {
    __shared__ int cur[FPN];
    const int slice = blockIdx.x >> 2;
    const int part = blockIdx.x & 3;
    const int base = part * FPN;
    for (int j = threadIdx.x; j < FPN; j += 1024) {
        int gi = base + j;
        cur[j] = (gi < NN) ? row_ofs[gi] + presum[slice * NPAD + gi] : 0;
    }
    __syncthreads();
    const int e0 = slice * ESL;
    for (int i = e0 + threadIdx.x; i < e0 + ESL; i += 1024) {
        int v = dst[i] - base;
        if ((unsigned)v < (unsigned)FPN) {
            int pos = atomicAdd(&cur[v], 1);
            eidx[pos] = src[i];
        }
    }
}

// ---------------- split-bf16 MFMA GEMM (fp32 A) ----------------
__global__ __launch_bounds__(256) void gemm1_kernel(
    const float* __restrict__ A, const unsigned short* __restrict__ Wh,
    const unsigned short* __restrict__ Wl, unsigned short* __restrict__ out, int M) {
    constexpr int N = 128, K = 256;
    constexpr int NT = N / 16, KC = K / 32;
    const int wave = threadIdx.x >> 6;
    const int lane = threadIdx.x & 63;
    const int ln = lane & 15;
    const int qk = lane >> 4;
    const int m0 = blockIdx.x * 64 + wave * 16;
    const int mA = m0 + ln;
    const bool a_ok = mA < M;
    const float* Arow = A + (size_t)(a_ok ? mA : (M - 1)) * K + qk * 8;
    const bf16x8* BH = (const bf16x8*)Wh;
    const bf16x8* BL = (const bf16x8*)Wl;

    f32x4 acc[NT];
#pragma unroll
    for (int t = 0; t < NT; t++) acc[t] = (f32x4){0.f, 0.f, 0.f, 0.f};

#pragma unroll 2
    for (int c = 0; c < KC; ++c) {
        float4 a0 = *(const float4*)(Arow + c * 32);
        float4 a1 = *(const float4*)(Arow + c * 32 + 4);
        float av[8] = {a0.x, a0.y, a0.z, a0.w, a1.x, a1.y, a1.z, a1.w};
        bf16x8 ah, al;
#pragma unroll
        for (int j = 0; j < 8; ++j) {
            unsigned u = f2u(av[j]);
            float lo = av[j] - u2f(u & 0xffff0000u);
            ah[j] = (short)(u >> 16);
            al[j] = (short)(f2u(lo) >> 16);
        }
        const int fb = c * 4 + qk;
#pragma unroll
        for (int t = 0; t < NT; ++t) {
            bf16x8 bh = BH[(t * (K / 8) + fb) * 16 + ln];
            bf16x8 bl = BL[(t * (K / 8) + fb) * 16 + ln];
            acc[t] = __builtin_amdgcn_mfma_f32_16x16x32_bf16(ah, bh, acc[t], 0, 0, 0);
            acc[t] = __builtin_amdgcn_mfma_f32_16x16x32_bf16(ah, bl, acc[t], 0, 0, 0);
            acc[t] = __builtin_amdgcn_mfma_f32_16x16x32_bf16(al, bh, acc[t], 0, 0, 0);
        }
    }
#pragma unroll
    for (int t = 0; t < NT; ++t)
#pragma unroll
        for (int r = 0; r < 4; ++r) {
            int row = m0 + qk * 4 + r;
            if (row < M) out[(size_t)row * N + t * 16 + ln] = f2bf(acc[t][r]);
        }
}

// ---------------- bf16-A MFMA GEMM (A exact bf16 -> only 2 MFMA terms) -------
__global__ __launch_bounds__(256) void gemm2_kernel(
    const unsigned short* __restrict__ A, const unsigned short* __restrict__ Wh,
    const unsigned short* __restrict__ Wl, unsigned short* __restrict__ out, int M) {
    constexpr int N = 64, K = 128;
    constexpr int NT = N / 16, KC = K / 32;
    const int wave = threadIdx.x >> 6;
    const int lane = threadIdx.x & 63;
    const int ln = lane & 15;
    const int qk = lane >> 4;
    const int m0 = blockIdx.x * 64 + wave * 16;
    const int mA = m0 + ln;
    const unsigned short* Arow = A + (size_t)(mA < M ? mA : (M - 1)) * K + qk * 8;
    const bf16x8* BH = (const bf16x8*)Wh;
    const bf16x8* BL = (const bf16x8*)Wl;

    f32x4 acc[NT];
#pragma unroll
    for (int t = 0; t < NT; t++) acc[t] = (f32x4){0.f, 0.f, 0.f, 0.f};

#pragma unroll
    for (int c = 0; c < KC; ++c) {
        bf16x8 ah = *(const bf16x8*)(Arow + c * 32);
        const int fb = c * 4 + qk;
#pragma unroll
        for (int t = 0; t < NT; ++t) {
            bf16x8 bh = BH[(t * (K / 8) + fb) * 16 + ln];
            bf16x8 bl = BL[(t * (K / 8) + fb) * 16 + ln];
            acc[t] = __builtin_amdgcn_mfma_f32_16x16x32_bf16(ah, bh, acc[t], 0, 0, 0);
            acc[t] = __builtin_amdgcn_mfma_f32_16x16x32_bf16(ah, bl, acc[t], 0, 0, 0);
        }
    }
#pragma unroll
    for (int t = 0; t < NT; ++t)
#pragma unroll
        for (int r = 0; r < 4; ++r) {
            int row = m0 + qk * 4 + r;
            if (row < M) out[(size_t)row * N + t * 16 + ln] = f2bf(acc[t][r]);
        }
}

// ---------------- CSR gather-sum (bf16, per-edge src-norm) + epilogue ----------
// D=128: one wave per dst node, lane owns 2 dims; 4 edges in flight. bf16 out.
__global__ __launch_bounds__(256) void gather128_kernel(
    const unsigned* __restrict__ hs, const int* __restrict__ eidx,
    const int* __restrict__ row_ofs, const float* __restrict__ norm_src,
    const float* __restrict__ norm_dst, const float* __restrict__ bias,
    unsigned* __restrict__ out, int n) {
    int wave = (blockIdx.x * blockDim.x + threadIdx.x) >> 6;
    int lane = threadIdx.x & 63;
    if (wave >= n) return;
    int beg = row_ofs[wave], end = row_ofs[wave + 1];
    float sc = norm_dst[wave];
    float ax = 0.f, ay = 0.f;
    int e = beg;
    for (; e + 3 < end; e += 4) {
        int s0 = eidx[e], s1 = eidx[e + 1], s2 = eidx[e + 2], s3 = eidx[e + 3];
        float n0 = norm_src[s0], n1 = norm_src[s1];
        float n2 = norm_src[s2], n3 = norm_src[s3];
        unsigned u0 = hs[(size_t)s0 * 64 + lane];
        unsigned u1 = hs[(size_t)s1 * 64 + lane];
        unsigned u2 = hs[(size_t)s2 * 64 + lane];
        unsigned u3 = hs[(size_t)s3 * 64 + lane];
        ax += n0 * u2f(u0 << 16) + n1 * u2f(u1 << 16) +
              n2 * u2f(u2 << 16) + n3 * u2f(u3 << 16);
        ay += n0 * u2f(u0 & 0xffff0000u) + n1 * u2f(u1 & 0xffff0000u) +
              n2 * u2f(u2 & 0xffff0000u) + n3 * u2f(u3 & 0xffff0000u);
    }
    for (; e < end; ++e) {
        int s0 = eidx[e];
        float n0 = norm_src[s0];
        unsigned u0 = hs[(size_t)s0 * 64 + lane];
        ax += n0 * u2f(u0 << 16);
        ay += n0 * u2f(u0 & 0xffff0000u);
    }
    float2 b = ((const float2*)bias)[lane];
    float rx = fmaxf(ax * sc + b.x, 0.f);   // relu
    float ry = fmaxf(ay * sc + b.y, 0.f);
    out[(size_t)wave * 64 + lane] = (unsigned)f2bf(rx) | ((unsigned)f2bf(ry) << 16);
}

// D=64: one wave per dst node; half-wave per edge; 2 edges in flight per half.
__global__ __launch_bounds__(256) void gather64_kernel(
    const unsigned* __restrict__ hs, const int* __restrict__ eidx,
    const int* __restrict__ row_ofs, const float* __restrict__ norm_src,
    const float* __restrict__ norm_dst, const float* __restrict__ bias,
    float* __restrict__ out, int n) {
    int wave = (blockIdx.x * blockDim.x + threadIdx.x) >> 6;
    int lane = threadIdx.x & 63;
    if (wave >= n) return;
    int beg = row_ofs[wave], end = row_ofs[wave + 1];
    int half = lane >> 5;
    int dim = lane & 31;
    float ax = 0.f, ay = 0.f;
    int e = beg + half;
    for (; e + 2 < end; e += 4) {
        int s0 = eidx[e], s1 = eidx[e + 2];
        float n0 = norm_src[s0], n1 = norm_src[s1];
        unsigned u0 = hs[(size_t)s0 * 32 + dim];
        unsigned u1 = hs[(size_t)s1 * 32 + dim];
        ax += n0 * u2f(u0 << 16) + n1 * u2f(u1 << 16);
        ay += n0 * u2f(u0 & 0xffff0000u) + n1 * u2f(u1 & 0xffff0000u);
    }
    if (e < end) {
        int s0 = eidx[e];
        float n0 = norm_src[s0];
        unsigned u0 = hs[(size_t)s0 * 32 + dim];
        ax += n0 * u2f(u0 << 16);
        ay += n0 * u2f(u0 & 0xffff0000u);
    }
    ax += __shfl_xor(ax, 32);
    ay += __shfl_xor(ay, 32);
    if (half == 0) {
        float sc = norm_dst[wave];
        float2 b = ((const float2*)bias)[dim];
        ((float2*)out)[(size_t)wave * 32 + dim] =
            make_float2(ax * sc + b.x, ay * sc + b.y);
    }
}

extern "C" void kernel_launch(void* const* d_in, const int* in_sizes, int n_in,
                              void* d_out, int out_size, void* d_ws, size_t ws_size,
                              hipStream_t stream) {
    const float* x  = (const float*)d_in[0];   // [50000,256]
    const float* W1 = (const float*)d_in[1];   // [256,128]
    const float* b1 = (const float*)d_in[2];   // [128]
    const float* W2 = (const float*)d_in[3];   // [128,64]
    const float* b2 = (const float*)d_in[4];   // [64]
    const int* src  = (const int*)d_in[5];     // [800000]
    const int* dst  = (const int*)d_in[6];     // [800000]
    float* out = (float*)d_out;                // [50000,64] fp32
    char* ws = (char*)d_ws;

    const int NB = (NN + 255) / 256;   // 196

    // ws layout (dword offsets)
    float* norm_src = (float*)(ws);                       // 50176
    float* norm_dst = (float*)(ws + 4 * 50176);           // 50176
    int*   row_ofs  = (int*)(ws + 4 * 100352);            // 50432
    int*   blk_sum  = (int*)(ws + 4 * 150784);            // 256
    int*   blk_ofs  = (int*)(ws + 4 * 151040);            // 256
    int*   eidx     = (int*)(ws + 4 * 151296);            // 800000
    unsigned short* Wh1 = (unsigned short*)(ws + 4 * 951296);   // 16384 dw
    unsigned short* Wl1 = (unsigned short*)(ws + 4 * 967680);   // 16384 dw
    unsigned short* Wh2 = (unsigned short*)(ws + 4 * 984064);   // 4096 dw
    unsigned short* Wl2 = (unsigned short*)(ws + 4 * 988160);   // 4096 dw
    unsigned short* hs1 = (unsigned short*)(ws + 4 * 992256);   // bf16 [50000,128]
    unsigned short* hs2 = (unsigned short*)(ws + 4 * 4192256);  // bf16 [50000,64]
    unsigned* cnt_sl    = (unsigned*)(ws + 4 * 5792256);        // 128*12544 dw
    int* presum         = (int*)(ws + 4 * 7397888);             // 32*50176 dw
    // h1 (bf16 [50000,128] = 3.2M dw) overlays cnt_sl+presum (both dead by then)
    unsigned short* h1  = (unsigned short*)(ws + 4 * 5792256);
    // end 9,003,520 dw ≈ 36 MB

    wtrans_kernel<<<160, 256, 0, stream>>>(W1, W2, Wh1, Wl1, Wh2, Wl2);

    hist_kernel<<<128, 1024, 0, stream>>>(src, dst, cnt_sl);
    gemm1_kernel<<<GB, 256, 0, stream>>>(x, Wh1, Wl1, hs1, NN);

    norm_scanA_kernel<<<NB, 256, 0, stream>>>(cnt_sl, norm_src, norm_dst,
                                              presum, row_ofs, blk_sum, NN);
    scanB_kernel<<<1, 256, 0, stream>>>(blk_sum, blk_ofs, NB);
    scanC_kernel<<<NB, 256, 0, stream>>>(row_ofs, blk_ofs, NN);
    fill_kernel<<<128, 1024, 0, stream>>>(src, dst, row_ofs, presum, eidx);

    gather128_kernel<<<(NN + 3) / 4, 256, 0, stream>>>(
        (const unsigned*)hs1, eidx, row_ofs, norm_src, norm_dst, b1,
        (unsigned*)h1, NN);

    gemm2_kernel<<<GB, 256, 0, stream>>>(h1, Wh2, Wl2, hs2, NN);

    gather64_kernel<<<(NN + 3) / 4, 256, 0, stream>>>(
        (const unsigned*)hs2, eidx, row_ofs, norm_src, norm_dst, b2, out, NN);
}